// Round 5
// baseline (2636.409 us; speedup 1.0000x reference)
//
#include <hip/hip_runtime.h>
#include <math.h>

// ---------------------------------------------------------------------------
// DyRes/CondConv AlexNet forward. R12: conv GEMM rebuilt around a 256x256
// tile (4 waves, wave tile 128x128, mi=ni=8) to halve LDS bytes per MFMA.
//  - acc = 256 AGPR -> experts return to blockIdx.z (epilogue r-scale +
//    fp32 atomicAdd into memset slab). No accS.
//  - Staging via global_load_lds (16B DMA, no reg round-trip, no stage VALU).
//    LDS linear (DMA requirement); bank conflicts fixed by XOR-swizzling the
//    per-lane GLOBAL source slot (A: slot^((row>>1)&3), B: slot^(row&7));
//    reads apply the same XOR -> 2-way max.
//  - One raw barrier per K-step: {vmcnt(0) lgkmcnt(0); s_barrier}; next-step
//    DMA issued right after the barrier flies across the compute phase.
//  - Activations stay packed u32 (pool/pack/stats kernels unchanged); B is
//    unpacked to bf16 hi/lo at fragment read (VALU well under MFMA).
// L1 conv + FC mgemm + all elementwise kernels unchanged from R10.
// ---------------------------------------------------------------------------

typedef unsigned short u16;
typedef unsigned int u32;
typedef short bf16x8 __attribute__((ext_vector_type(8)));
typedef float f32x4 __attribute__((ext_vector_type(4)));

__device__ __forceinline__ u16 bf16_rne(float f) {
    u32 u = __float_as_uint(f);
    return (u16)((u + 0x7fffu + ((u >> 16) & 1u)) >> 16);
}
__device__ __forceinline__ u32 packsplit(float v) {
    u16 h = bf16_rne(v);
    float hf = __uint_as_float((u32)h << 16);
    u16 l = bf16_rne(v - hf);
    return ((u32)h << 16) | l;
}
__device__ __forceinline__ float unpackf(u32 p) {
    return __uint_as_float(p & 0xffff0000u) + __uint_as_float(p << 16);
}
__device__ __forceinline__ int xcd_swz(int bid, int n) {
    if ((n & 7) != 0) return bid;
    int cpx = n >> 3;
    return (bid & 7) * cpx + (bid >> 3);
}

// fp32 weights -> K-padded bf16 hi/lo planes, source k-order (ci,kh,kw)
__global__ __launch_bounds__(256)
void wsplit_kernel(const float* __restrict__ W, u16* __restrict__ whi,
                   u16* __restrict__ wlo, int total, int Kper, int Kpad)
{
    int idx = blockIdx.x * 256 + threadIdx.x;
    if (idx >= total) return;
    int r = idx / Kpad, k = idx - r * Kpad;
    float v = (k < Kper) ? W[(size_t)r * Kper + k] : 0.f;
    u16 h = bf16_rne(v);
    whi[idx] = h;
    wlo[idx] = bf16_rne(v - __uint_as_float((u32)h << 16));
}

// fp32 weights -> bf16 hi/lo planes with k-order permuted to (kh,kw,ci)
__global__ __launch_bounds__(256)
void wsplit_cl_kernel(const float* __restrict__ W, u16* __restrict__ whi,
                      u16* __restrict__ wlo, int total, int Ci)
{
    int idx = blockIdx.x * 256 + threadIdx.x;
    if (idx >= total) return;
    int Kper = 9 * Ci;
    int r = idx / Kper, kp = idx - r * Kper;
    int cell = kp / Ci, ci = kp - cell * Ci;
    float v = W[(size_t)r * Kper + ci * 9 + cell];
    u16 h = bf16_rne(v);
    whi[idx] = h;
    wlo[idx] = bf16_rne(v - __uint_as_float((u32)h << 16));
}

// stats over fp32 [B][C][HW] (layer-1 input only)
__global__ __launch_bounds__(64)
void stats_kernel(const float* __restrict__ actv, float* __restrict__ s,
                  int C, int HW, int use_std)
{
    int idx = blockIdx.x;
    size_t base = (size_t)idx * HW;
    int lane = threadIdx.x;
    float sum = 0.f, sq = 0.f;
    const float* p = actv + base;
    for (int i = lane; i < HW; i += 64) { float v = p[i]; sum += v; sq += v * v; }
#pragma unroll
    for (int off = 32; off > 0; off >>= 1) {
        sum += __shfl_down(sum, off);
        sq  += __shfl_down(sq, off);
    }
    if (lane == 0) {
        float inv = 1.f / (float)HW;
        float mean = sum * inv;
        float var = sq * inv - mean * mean;
        float outv = mean;
        if (use_std) outv += sqrtf(fmaxf(var, 0.f));
        s[idx] = outv;
    }
}

// stats over packed channels-last halo'd act [B][H2][W2][C]; block=C, grid=B
__global__ __launch_bounds__(384)
void stats_cl_kernel(const u32* __restrict__ act, float* __restrict__ s,
                     int H2, int W2, int C, int use_std)
{
    int b = blockIdx.x, c = threadIdx.x;
    int Hin = H2 - 2, Win = W2 - 2;
    float sum = 0.f, sq = 0.f;
    for (int h = 0; h < Hin; ++h)
        for (int w = 0; w < Win; ++w) {
            float v = unpackf(act[(((size_t)b * H2 + h + 1) * W2 + w + 1) * C + c]);
            sum += v; sq += v * v;
        }
    float inv = 1.f / (float)(Hin * Win);
    float mean = sum * inv;
    float var = sq * inv - mean * mean;
    float outv = mean;
    if (use_std) outv += sqrtf(fmaxf(var, 0.f));
    s[b * C + c] = outv;
}

__global__ __launch_bounds__(64)
void routing_kernel(const float* __restrict__ s, const float* __restrict__ rw,
                    const float* __restrict__ rb, float* __restrict__ r,
                    int C, int softmax_mode)
{
    int b = blockIdx.x;
    int lane = threadIdx.x;
    float d0 = 0.f, d1 = 0.f, d2 = 0.f;
    for (int c = lane; c < C; c += 64) {
        float sv = s[b * C + c];
        d0 += sv * rw[c];
        d1 += sv * rw[C + c];
        d2 += sv * rw[2 * C + c];
    }
#pragma unroll
    for (int off = 32; off > 0; off >>= 1) {
        d0 += __shfl_down(d0, off);
        d1 += __shfl_down(d1, off);
        d2 += __shfl_down(d2, off);
    }
    if (lane == 0) {
        d0 += rb[0]; d1 += rb[1]; d2 += rb[2];
        if (softmax_mode) {
            float mx = fmaxf(d0, fmaxf(d1, d2));
            float e0 = expf(d0 - mx), e1 = expf(d1 - mx), e2 = expf(d2 - mx);
            float inv = 1.f / (e0 + e1 + e2);
            r[b * 3 + 0] = e0 * inv;
            r[b * 3 + 1] = e1 * inv;
            r[b * 3 + 2] = e2 * inv;
        } else {
            r[b * 3 + 0] = 1.f / (1.f + expf(-d0));
            r[b * 3 + 1] = 1.f / (1.f + expf(-d1));
            r[b * 3 + 2] = 1.f / (1.f + expf(-d2));
        }
    }
}

// ---------------------------------------------------------------------------
// Channels-last conv GEMM, 256Mx256N tile, BK=32, 4 waves (2x2), wave tile
// 128x128 (mi=ni=8). z = expert*kz + k-chunk. DMA staging (global_load_lds,
// 16B) with source-side XOR swizzle; one raw barrier per step. Epilogue:
// acc * r[b,e] -> fp32 atomicAdd into pre-zeroed Cout (transposed C[n][m]).
// A rows >= M read mapped garbage (masked at write). Lanes: lm=lane&15 (col),
// qd=lane>>4 (row quad) per verified 16x16x32 C layout.
// ---------------------------------------------------------------------------
template<int CI, int H2, int W2, int LGS, int LGOW>
__global__ __launch_bounds__(256, 1)
void cgemm_cl_kernel(const u16* __restrict__ Whi, const u16* __restrict__ Wlo,
                     const u32* __restrict__ Bpk, const float* __restrict__ rptr,
                     float* __restrict__ Cout, int M, int N, int Kper,
                     int Kchunk, int kz)
{
    // per buf: Ah [256][32] u16 (16KB) + Al (16KB) + Bp [256][32] u32 (32KB)
    __shared__ __align__(16) u16 AhS[2][256 * 32];
    __shared__ __align__(16) u16 AlS[2][256 * 32];
    __shared__ __align__(16) u32 BpS[2][256 * 32];

    const int tid = threadIdx.x;
    const int lane = tid & 63, wv = tid >> 6;
    const int bx = xcd_swz(blockIdx.x, gridDim.x);
    const int n0 = bx << 8, m0 = blockIdx.y << 8;
    const int bz = blockIdx.z;
    const int eA = bz / kz;
    const int kq0 = (bz - eA * kz) * Kchunk;

    const int lm = lane & 15, qd = lane >> 4;
    const int wm = (wv & 1) << 7, wn = (wv >> 1) << 7;

    // ---- per-lane DMA source offsets (k-independent part) ----
    // wv 0: A-hi, wv 1: A-lo  (16 issues x 1KB cover [256][32] u16)
    // wv 2: B rows 0..127, wv 3: B rows 128..255 (16 issues x 1KB each)
    u32 offs[16];
    if (wv < 2) {
#pragma unroll
        for (int i = 0; i < 16; ++i) {
            int row = i * 16 + (lane >> 2);
            int slot = (lane & 3) ^ ((row >> 1) & 3);      // src-side swizzle
            offs[i] = (u32)((m0 + row) * Kper + slot * 8); // u16 units
        }
    } else {
        int rbase = (wv - 2) * 128;
#pragma unroll
        for (int i = 0; i < 16; ++i) {
            int row = rbase + i * 8 + (lane >> 3);
            int slot = (lane & 7) ^ (row & 7);             // src-side swizzle
            int n = n0 + row;
            int bB = n >> LGS;
            int sidx = n & ((1 << LGS) - 1);
            int oh = sidx >> LGOW, ow = sidx & ((1 << LGOW) - 1);
            offs[i] = (u32)(((bB * H2 + oh) * W2 + ow) * CI + slot * 4); // u32
        }
    }

    f32x4 acc[8][8];
#pragma unroll
    for (int i = 0; i < 8; ++i)
#pragma unroll
        for (int j = 0; j < 8; ++j)
            acc[i][j] = (f32x4){0.f, 0.f, 0.f, 0.f};

    const size_t aScalBase = (size_t)eA * M * Kper;

    auto ISSUE = [&](int buf, int kI) {
        if (wv < 2) {
            const u16* gp = ((wv == 0) ? Whi : Wlo) + aScalBase + kI;
            u16* lp = (wv == 0) ? &AhS[buf][0] : &AlS[buf][0];
#pragma unroll
            for (int i = 0; i < 16; ++i)
                __builtin_amdgcn_global_load_lds(gp + offs[i], lp + i * 512, 16, 0, 0);
        } else {
            int cell = kI / CI;
            int ci0 = kI - cell * CI;
            int kh = (cell * 11) >> 5;
            int kw = cell - kh * 3;
            const u32* gp = Bpk + ((kh * W2 + kw) * CI + ci0);
            u32* lp = &BpS[buf][(wv - 2) * 4096];
#pragma unroll
            for (int i = 0; i < 16; ++i)
                __builtin_amdgcn_global_load_lds(gp + offs[i], lp + i * 256, 16, 0, 0);
        }
    };

    const int xm = (lm >> 1) & 3;   // A read-side XOR (lane-only, all rows)

    auto COMPUTE = [&](int buf) {
        bf16x8 ah[8], al[8];
#pragma unroll
        for (int mi = 0; mi < 8; ++mi) {
            int row = wm + mi * 16 + lm;
            int off = row * 32 + ((qd ^ xm) * 8);   // u16 units
            ah[mi] = *(const bf16x8*)&AhS[buf][off];
            al[mi] = *(const bf16x8*)&AlS[buf][off];
        }
        __builtin_amdgcn_s_setprio(1);
#pragma unroll
        for (int ni = 0; ni < 8; ++ni) {
            int row = wn + ni * 16 + lm;
            int sw = row & 7;
            const u32* bp = &BpS[buf][row * 32];
            uint4 p0 = *(const uint4*)(bp + (((2 * qd) ^ sw) * 4));
            uint4 p1 = *(const uint4*)(bp + (((2 * qd + 1) ^ sw) * 4));
            union { u32 w[4]; bf16x8 v; } bh, bl;
            bh.w[0] = (p0.x >> 16) | (p0.y & 0xffff0000u);
            bl.w[0] = (p0.x & 0xffffu) | (p0.y << 16);
            bh.w[1] = (p0.z >> 16) | (p0.w & 0xffff0000u);
            bl.w[1] = (p0.z & 0xffffu) | (p0.w << 16);
            bh.w[2] = (p1.x >> 16) | (p1.y & 0xffff0000u);
            bl.w[2] = (p1.x & 0xffffu) | (p1.y << 16);
            bh.w[3] = (p1.z >> 16) | (p1.w & 0xffff0000u);
            bl.w[3] = (p1.z & 0xffffu) | (p1.w << 16);
#pragma unroll
            for (int mi = 0; mi < 8; ++mi) {
                f32x4 c = acc[mi][ni];
                c = __builtin_amdgcn_mfma_f32_16x16x32_bf16(al[mi], bh.v, c, 0, 0, 0);
                c = __builtin_amdgcn_mfma_f32_16x16x32_bf16(ah[mi], bl.v, c, 0, 0, 0);
                c = __builtin_amdgcn_mfma_f32_16x16x32_bf16(ah[mi], bh.v, c, 0, 0, 0);
                acc[mi][ni] = c;
            }
        }
        __builtin_amdgcn_s_setprio(0);
    };

    const int NS = Kchunk >> 5;
    int kI = kq0;
    ISSUE(0, kI); kI += 32;
    int buf = 0;
    for (int s = 0; s < NS; ++s) {
        // drain THIS buf's DMA + own trailing LDS reads, then sync. Next-step
        // loads (issued below) stay in flight across compute + next barrier.
        asm volatile("s_waitcnt vmcnt(0) lgkmcnt(0)\n\ts_barrier" ::: "memory");
        if (s + 1 < NS) { ISSUE(buf ^ 1, kI); kI += 32; }
        COMPUTE(buf);
        buf ^= 1;
    }

    // ---- epilogue: r-scale, fp32 atomicAdd (Cout pre-zeroed) ----
#pragma unroll
    for (int ni = 0; ni < 8; ++ni) {
        int n = n0 + wn + ni * 16 + lm;
        float rs = rptr[(n >> LGS) * 3 + eA];
#pragma unroll
        for (int mi = 0; mi < 8; ++mi)
#pragma unroll
            for (int r = 0; r < 4; ++r) {
                int m = m0 + wm + mi * 16 + qd * 4 + r;
                if (m >= M) continue;
                atomicAdd(&Cout[(size_t)n * M + m], acc[mi][ni][r] * rs);
            }
    }
}

// ---------------------------------------------------------------------------
// Layer-1 conv GEMM (Ci=3, stride 2): gather path, transposed output.
// ---------------------------------------------------------------------------
__global__ __launch_bounds__(256, 2)
void cgemm_l1_kernel(const u16* __restrict__ Whi, const u16* __restrict__ Wlo,
                     const u32* __restrict__ Bpk, const float* __restrict__ rptr,
                     float* __restrict__ Cout, int M, int N)
{
    __shared__ __align__(16) u16 Ah[2][128 * 40], Al[2][128 * 40];
    __shared__ __align__(16) u16 Bh[2][128 * 40], Bl[2][128 * 40];
    const int tid = threadIdx.x;
    const int bx = xcd_swz(blockIdx.x, gridDim.x);
    const int n0 = bx << 7;
    const int Kper = 27, Kpad = 32;
    const int H = 32, W = 32;

    const int rowA = tid >> 1, kh16 = (tid & 1) << 4;
    const int nB = tid & 127, kOff = (tid >> 7) << 4;

    const int nn = n0 + nB;
    const int bB = nn >> 8;
    const int sidx = nn & 255;
    const int ohs = (sidx >> 4) * 2 - 1;
    const int ows = (sidx & 15) * 2 - 1;
    const long nBase = (long)bB * 3072 + (long)ohs * W + ows;

    const int lane = tid & 63, wv = tid >> 6;
    const int lm = lane & 15, qd = lane >> 4;
    const int wm = (wv & 1) << 6, wn = (wv >> 1) << 6;

    float rsv[3][4];
#pragma unroll
    for (int ni = 0; ni < 4; ++ni) {
        int n = n0 + wn + ni * 16 + lm;
        int b = n >> 8;
#pragma unroll
        for (int e = 0; e < 3; ++e) rsv[e][ni] = rptr[b * 3 + e];
    }

    f32x4 acc[4][4], accS[4][4];
#pragma unroll
    for (int i = 0; i < 4; ++i)
#pragma unroll
        for (int j = 0; j < 4; ++j) {
            acc[i][j]  = (f32x4){0.f, 0.f, 0.f, 0.f};
            accS[i][j] = (f32x4){0.f, 0.f, 0.f, 0.f};
        }

    const int mg = rowA;
    int eL = 0;
    uint4 pA0, pA1, pA2, pA3;
    u32 pB[16];

    auto LOAD = [&]() {
        size_t aOff = ((size_t)(eL * M + mg)) * Kpad + kh16;
        const u16* hp = Whi + aOff;
        const u16* lp = Wlo + aOff;
        pA0 = *(const uint4*)hp; pA1 = *(const uint4*)(hp + 8);
        pA2 = *(const uint4*)lp; pA3 = *(const uint4*)(lp + 8);
#pragma unroll
        for (int j = 0; j < 16; ++j) {
            int k = kOff + j;
            int ci = (int)((unsigned)k / 9u);
            int r9 = k - ci * 9;
            int kh = (int)(((unsigned)r9 * 11u) >> 5);
            int kw = r9 - kh * 3;
            int ih = ohs + kh, iw = ows + kw;
            u32 p = 0;
            if (k < Kper && (unsigned)ih < (unsigned)H && (unsigned)iw < (unsigned)W)
                p = Bpk[nBase + (long)ci * 1024 + kh * W + kw];
            pB[j] = p;
        }
    };
    auto STORE = [&](int buf) {
        *(uint4*)(&Ah[buf][rowA * 40 + kh16])     = pA0;
        *(uint4*)(&Ah[buf][rowA * 40 + kh16 + 8]) = pA1;
        *(uint4*)(&Al[buf][rowA * 40 + kh16])     = pA2;
        *(uint4*)(&Al[buf][rowA * 40 + kh16 + 8]) = pA3;
        u32 hw[8], lw[8];
#pragma unroll
        for (int j = 0; j < 8; ++j) {
            u32 p0 = pB[2 * j], p1 = pB[2 * j + 1];
            hw[j] = (p0 >> 16) | (p1 & 0xffff0000u);
            lw[j] = (p0 & 0xffffu) | (p1 << 16);
        }
        *(uint4*)(&Bh[buf][nB * 40 + kOff])     = make_uint4(hw[0], hw[1], hw[2], hw[3]);
        *(uint4*)(&Bh[buf][nB * 40 + kOff + 8]) = make_uint4(hw[4], hw[5], hw[6], hw[7]);
        *(uint4*)(&Bl[buf][nB * 40 + kOff])     = make_uint4(lw[0], lw[1], lw[2], lw[3]);
        *(uint4*)(&Bl[buf][nB * 40 + kOff + 8]) = make_uint4(lw[4], lw[5], lw[6], lw[7]);
    };
    auto COMPUTE = [&](int buf) {
        bf16x8 ah[4], al[4];
#pragma unroll
        for (int mi = 0; mi < 4; ++mi) {
            int row = wm + mi * 16 + lm;
            ah[mi] = *(const bf16x8*)(&Ah[buf][row * 40 + qd * 8]);
            al[mi] = *(const bf16x8*)(&Al[buf][row * 40 + qd * 8]);
        }
        __builtin_amdgcn_s_setprio(1);
#pragma unroll
        for (int ni = 0; ni < 4; ++ni) {
            int row = wn + ni * 16 + lm;
            bf16x8 bh = *(const bf16x8*)(&Bh[buf][row * 40 + qd * 8]);
            bf16x8 bl = *(const bf16x8*)(&Bl[buf][row * 40 + qd * 8]);
#pragma unroll
            for (int mi = 0; mi < 4; ++mi) {
                f32x4 c = acc[mi][ni];
                c = __builtin_amdgcn_mfma_f32_16x16x32_bf16(al[mi], bh, c, 0, 0, 0);
                c = __builtin_amdgcn_mfma_f32_16x16x32_bf16(ah[mi], bl, c, 0, 0, 0);
                c = __builtin_amdgcn_mfma_f32_16x16x32_bf16(ah[mi], bh, c, 0, 0, 0);
                acc[mi][ni] = c;
            }
        }
        __builtin_amdgcn_s_setprio(0);
    };

    LOAD(); ++eL;
    int buf = 0;
#pragma unroll
    for (int e = 0; e < 3; ++e) {
        STORE(buf);
        if (e < 2) { LOAD(); ++eL; }
        asm volatile("s_waitcnt lgkmcnt(0)\n\ts_barrier" ::: "memory");
        COMPUTE(buf);
        buf ^= 1;
#pragma unroll
        for (int mi = 0; mi < 4; ++mi)
#pragma unroll
            for (int ni = 0; ni < 4; ++ni) {
                accS[mi][ni] += acc[mi][ni] * rsv[e][ni];
                acc[mi][ni] = (f32x4){0.f, 0.f, 0.f, 0.f};
            }
    }

#pragma unroll
    for (int ni = 0; ni < 4; ++ni) {
        int n = n0 + wn + ni * 16 + lm;
#pragma unroll
        for (int mi = 0; mi < 4; ++mi)
#pragma unroll
            for (int r = 0; r < 4; ++r) {
                int m = wm + mi * 16 + qd * 4 + r;
                if (m >= M) continue;
                Cout[(size_t)n * M + m] = accS[mi][ni][r];
            }
    }
}

// ---------------------------------------------------------------------------
// FC GEMM: 128Mx128N tile, BK=32, split-K atomics. (proven R7 form)
// ---------------------------------------------------------------------------
template<int BIAS, int TROUT>
__global__ __launch_bounds__(256)
void mgemm_kernel(const u16* __restrict__ Whi, const u16* __restrict__ Wlo,
                  const u32* __restrict__ Bpk, const float* __restrict__ bias,
                  float* __restrict__ Cout,
                  int M, int N, int Kpad, int Kchunk)
{
    __shared__ __align__(16) u16 Ah[128 * 40], Al[128 * 40];
    __shared__ __align__(16) u32 Bp[128 * 36];
    const int tid = threadIdx.x;
    const int n0 = blockIdx.x << 7, m0 = blockIdx.y << 7;
    const int bz = blockIdx.z;
    const int kq0 = bz * Kchunk;

    const int rowA = tid >> 1, kh16 = (tid & 1) << 4;
    const int nB = tid & 127, kOff = (tid >> 7) << 4;

    const int lane = tid & 63, wv = tid >> 6;
    const int lm = lane & 15, qd = lane >> 4;
    const int wm = (wv & 1) << 6, wn = (wv >> 1) << 6;

    f32x4 acc[4][4];
#pragma unroll
    for (int i = 0; i < 4; ++i)
#pragma unroll
        for (int j = 0; j < 4; ++j)
            acc[i][j] = (f32x4){0.f, 0.f, 0.f, 0.f};

    for (int kq = kq0; kq < kq0 + Kchunk; kq += 32) {
        {
            int mg = m0 + rowA;
            uint4 h0 = {0,0,0,0}, h1 = {0,0,0,0}, l0 = {0,0,0,0}, l1 = {0,0,0,0};
            if (mg < M) {
                const u16* hp = Whi + (size_t)mg * Kpad + kq + kh16;
                const u16* lp = Wlo + (size_t)mg * Kpad + kq + kh16;
                h0 = *(const uint4*)hp; h1 = *(const uint4*)(hp + 8);
                l0 = *(const uint4*)lp; l1 = *(const uint4*)(lp + 8);
            }
            *(uint4*)(&Ah[rowA * 40 + kh16])     = h0;
            *(uint4*)(&Ah[rowA * 40 + kh16 + 8]) = h1;
            *(uint4*)(&Al[rowA * 40 + kh16])     = l0;
            *(uint4*)(&Al[rowA * 40 + kh16 + 8]) = l1;
        }
        {
            const u32* bp = Bpk + (size_t)(n0 + nB) * Kpad + kq + kOff;
            uint4 q0 = *(const uint4*)bp;
            uint4 q1 = *(const uint4*)(bp + 4);
            uint4 q2 = *(const uint4*)(bp + 8);
            uint4 q3 = *(const uint4*)(bp + 12);
            *(uint4*)(&Bp[nB * 36 + kOff])      = q0;
            *(uint4*)(&Bp[nB * 36 + kOff + 4])  = q1;
            *(uint4*)(&Bp[nB * 36 + kOff + 8])  = q2;
            *(uint4*)(&Bp[nB * 36 + kOff + 12]) = q3;
        }
        __syncthreads();
        {
            bf16x8 ah[4], al[4];
#pragma unroll
            for (int mi = 0; mi < 4; ++mi) {
                int row = wm + mi * 16 + lm;
                ah[mi] = *(const bf16x8*)(&Ah[row * 40 + qd * 8]);
                al[mi] = *(const bf16x8*)(&Al[row * 40 + qd * 8]);
            }
#pragma unroll
            for (int ni = 0; ni < 4; ++ni) {
                int row = wn + ni * 16 + lm;
                const u32* bp = &Bp[row * 36 + qd * 8];
                uint4 p0 = *(const uint4*)bp;
                uint4 p1 = *(const uint4*)(bp + 4);
                union { u32 w[4]; bf16x8 v; } bh, bl;
                bh.w[0] = (p0.x >> 16) | (p0.y & 0xffff0000u);
                bl.w[0] = (p0.x & 0xffffu) | (p0.y << 16);
                bh.w[1] = (p0.z >> 16) | (p0.w & 0xffff0000u);
                bl.w[1] = (p0.z & 0xffffu) | (p0.w << 16);
                bh.w[2] = (p1.x >> 16) | (p1.y & 0xffff0000u);
                bl.w[2] = (p1.x & 0xffffu) | (p1.y << 16);
                bh.w[3] = (p1.z >> 16) | (p1.w & 0xffff0000u);
                bl.w[3] = (p1.z & 0xffffu) | (p1.w << 16);
#pragma unroll
                for (int mi = 0; mi < 4; ++mi) {
                    f32x4 c = acc[mi][ni];
                    c = __builtin_amdgcn_mfma_f32_16x16x32_bf16(al[mi], bh.v, c, 0, 0, 0);
                    c = __builtin_amdgcn_mfma_f32_16x16x32_bf16(ah[mi], bl.v, c, 0, 0, 0);
                    c = __builtin_amdgcn_mfma_f32_16x16x32_bf16(ah[mi], bh.v, c, 0, 0, 0);
                    acc[mi][ni] = c;
                }
            }
        }
        __syncthreads();
    }

#pragma unroll
    for (int ni = 0; ni < 4; ++ni) {
        int n = n0 + wn + ni * 16 + lm;
        if (n >= N) continue;
#pragma unroll
        for (int mi = 0; mi < 4; ++mi)
#pragma unroll
            for (int r = 0; r < 4; ++r) {
                int m = m0 + wm + mi * 16 + qd * 4 + r;
                if (m >= M) continue;
                float v = acc[mi][ni][r];
                if (BIAS && bz == 0) v += bias[m];
                if (TROUT) atomicAdd(&Cout[(size_t)n * M + m], v);
                else       atomicAdd(&Cout[(size_t)m * N + n], v);
            }
    }
}

// elementwise fp32 -> packed bf16x2
__global__ __launch_bounds__(256)
void pack_kernel(const float* __restrict__ in, u32* __restrict__ outp, int count)
{
    int i = blockIdx.x * 256 + threadIdx.x;
    if (i >= count) return;
    outp[i] = packsplit(in[i]);
}

// 2x2/2 maxpool + relu: [B][Hin][Win][C] fp32 -> halo'd packed [B][OH+2][OW+2][C]
__global__ __launch_bounds__(256)
void pool_pack_cl_kernel(const float* __restrict__ in, u32* __restrict__ outp,
                         int Bn, int Hin, int Win, int C)
{
    int OH = Hin >> 1, OW = Win >> 1, H2 = OH + 2, W2 = OW + 2;
    int total = Bn * H2 * W2 * C;
    int i = blockIdx.x * 256 + threadIdx.x;
    if (i >= total) return;
    int c = i % C; int t = i / C;
    int w = t % W2; t /= W2;
    int h = t % H2; int b = t / H2;
    u32 pv = 0;
    if (h >= 1 && h <= OH && w >= 1 && w <= OW) {
        int oh = h - 1, ow = w - 1;
        const float* p = in + (((size_t)b * Hin + 2 * oh) * Win + 2 * ow) * C + c;
        size_t rs = (size_t)Win * C;
        float v = fmaxf(fmaxf(p[0], p[C]), fmaxf(p[rs], p[rs + C]));
        pv = packsplit(fmaxf(v, 0.f));
    }
    outp[i] = pv;
}

// relu (no pool): [B][Hin][Win][C] fp32 -> halo'd packed [B][Hin+2][Win+2][C]
__global__ __launch_bounds__(256)
void pack_cl_kernel(const float* __restrict__ in, u32* __restrict__ outp,
                    int Bn, int Hin, int Win, int C)
{
    int H2 = Hin + 2, W2 = Win + 2;
    int total = Bn * H2 * W2 * C;
    int i = blockIdx.x * 256 + threadIdx.x;
    if (i >= total) return;
    int c = i % C; int t = i / C;
    int w = t % W2; t /= W2;
    int h = t % H2; int b = t / H2;
    u32 pv = 0;
    if (h >= 1 && h <= Hin && w >= 1 && w <= Win) {
        float v = in[(((size_t)b * Hin + (h - 1)) * Win + (w - 1)) * C + c];
        pv = packsplit(fmaxf(v, 0.f));
    }
    outp[i] = pv;
}

// L5 out [B][4][4][256] fp32 --relu+pool--> packed hT[b][f]
__global__ __launch_bounds__(256)
void pool_flatten_cl_kernel(const float* __restrict__ in, u32* __restrict__ outp)
{
    int i = blockIdx.x * 256 + threadIdx.x;
    if (i >= 512 * 1024) return;
    int b = i >> 10;
    int f = i & 1023;
    int c = f >> 2, sp = f & 3;
    int oh = sp >> 1, ow = sp & 1;
    const float* p = in + (((size_t)b * 4 + 2 * oh) * 4 + 2 * ow) * 256 + c;
    float v = fmaxf(fmaxf(p[0], p[256]), fmaxf(p[1024], p[1024 + 256]));
    outp[i] = packsplit(fmaxf(v, 0.f));
}

// FC act: fp32 [Mt][Nt] --relu--> packed transposed [Nt][Mt]
__global__ __launch_bounds__(256)
void tp_pack_kernel(const float* __restrict__ in, u32* __restrict__ outp,
                    int Mt, int Nt)
{
    __shared__ float t[32][33];
    int tx = threadIdx.x & 31, ty = threadIdx.x >> 5;
    int mB = blockIdx.x << 5, nB = blockIdx.y << 5;
#pragma unroll
    for (int i = 0; i < 4; ++i) {
        int mm = ty + i * 8;
        t[mm][tx] = in[(size_t)(mB + mm) * Nt + nB + tx];
    }
    __syncthreads();
#pragma unroll
    for (int i = 0; i < 4; ++i) {
        int nn = ty + i * 8;
        float v = fmaxf(t[tx][nn], 0.f);
        outp[(size_t)(nB + nn) * Mt + mB + tx] = packsplit(v);
    }
}

extern "C" void kernel_launch(void* const* d_in, const int* in_sizes, int n_in,
                              void* d_out, int out_size, void* d_ws, size_t ws_size,
                              hipStream_t stream)
{
    const float* x    = (const float*)d_in[0];
    const float* dw1  = (const float*)d_in[1];
    const float* rw1  = (const float*)d_in[2];
    const float* rb1  = (const float*)d_in[3];
    const float* dw2  = (const float*)d_in[4];
    const float* rw2  = (const float*)d_in[5];
    const float* rb2  = (const float*)d_in[6];
    const float* dw3  = (const float*)d_in[7];
    const float* rw3  = (const float*)d_in[8];
    const float* rb3  = (const float*)d_in[9];
    const float* cw4  = (const float*)d_in[10];
    const float* cr4w = (const float*)d_in[11];
    const float* cr4b = (const float*)d_in[12];
    const float* cw5  = (const float*)d_in[13];
    const float* cr5w = (const float*)d_in[14];
    const float* cr5b = (const float*)d_in[15];
    const float* fw1  = (const float*)d_in[16];
    const float* fb1  = (const float*)d_in[17];
    const float* fw2  = (const float*)d_in[18];
    const float* fb2  = (const float*)d_in[19];
    const float* fw3  = (const float*)d_in[20];
    const float* fb3  = (const float*)d_in[21];
    float* out = (float*)d_out;

    // ---- workspace (float units); layout as R10 ----
    float* ws    = (float*)d_ws;
    float* r1    = ws;
    float* r2    = r1 + 1536;
    float* r3    = r2 + 1536;
    float* r4    = r3 + 1536;
    float* r5    = r4 + 1536;
    float* sdesc = ws + 8192 + 65536;
    const size_t REGION = 18874368;           // 75.5 MB region
    float* region = sdesc + 196608;
    float* slab   = region;                   // fp32 out-slab (front)
    u32*   a3u    = (u32*)(region + 4194304); // [512][6][6][384] packed u32
    u16*   regEnd = (u16*)(region + REGION);
    u32*   P1     = (u32*)(region + REGION);  // 6,291,456 u32 (25.2 MB)

    u16 *w1h = regEnd - 2*(size_t)6144,     *w1l = regEnd - (size_t)6144;
    u16 *w2h = regEnd - 2*(size_t)331776,   *w2l = regEnd - (size_t)331776;
    u16 *w3h = regEnd - 2*(size_t)1990656,  *w3l = regEnd - (size_t)1990656;
    u16 *w4h = regEnd - 2*(size_t)2654208,  *w4l = regEnd - (size_t)2654208;
    u16 *w5h = regEnd - 2*(size_t)1769472,  *w5l = regEnd - (size_t)1769472;
    u16 *f1h = regEnd - 2*(size_t)4194304,  *f1l = regEnd - (size_t)4194304;
    u16 *f2h = regEnd - 2*(size_t)16777216, *f2l = regEnd - (size_t)16777216;
    u16 *f3h = regEnd - 2*(size_t)409600,   *f3l = regEnd - (size_t)409600;

    u32* xpk   = P1;                 // [B][3][32][32]
    u32* a1    = P1;                 // [512][10][10][64]
    u32* a2    = P1;                 // [512][6][6][192]
    u32* a4    = P1;                 // [512][6][6][256]
    u32* hTpk  = P1;                 // [512][1024]
    u32* f1pkT = P1 + 1048576;
    u32* f2pkT = P1 + 3145728;

    const int B = 512;

    // ---- input pack ----
    pack_kernel<<<6144, 256, 0, stream>>>(x, xpk, 1572864);

    // ---- Layer 1: DyRes conv 3->64, s2 p1 -> slab [B][16][16][64] ----
    wsplit_kernel<<<24, 256, 0, stream>>>(dw1, w1h, w1l, 6144, 27, 32);
    stats_kernel<<<B * 3, 64, 0, stream>>>(x, sdesc, 3, 1024, 1);
    routing_kernel<<<B, 64, 0, stream>>>(sdesc, rw1, rb1, r1, 3, 1);
    cgemm_l1_kernel<<<dim3(1024, 1, 1), 256, 0, stream>>>(
        w1h, w1l, xpk, r1, slab, 64, 131072);
    pool_pack_cl_kernel<<<12800, 256, 0, stream>>>(slab, a1, B, 16, 16, 64);

    // ---- Layer 2: DyRes conv 64->192 -> slab [B][8][8][192] ----
    wsplit_cl_kernel<<<1296, 256, 0, stream>>>(dw2, w2h, w2l, 331776, 64);
    stats_cl_kernel<<<B, 64, 0, stream>>>(a1, sdesc, 10, 10, 64, 1);
    routing_kernel<<<B, 64, 0, stream>>>(sdesc, rw2, rb2, r2, 64, 1);
    hipMemsetAsync(slab, 0, (size_t)192 * 32768 * 4, stream);
    cgemm_cl_kernel<64, 10, 10, 6, 3><<<dim3(128, 1, 6), 256, 0, stream>>>(
        w2h, w2l, a1, r2, slab, 192, 32768, 576, 288, 2);
    pool_pack_cl_kernel<<<13824, 256, 0, stream>>>(slab, a2, B, 8, 8, 192);

    // ---- Layer 3: DyRes conv 192->384 -> slab [B][4][4][384] ----
    wsplit_cl_kernel<<<7776, 256, 0, stream>>>(dw3, w3h, w3l, 1990656, 192);
    stats_cl_kernel<<<B, 192, 0, stream>>>(a2, sdesc, 6, 6, 192, 1);
    routing_kernel<<<B, 64, 0, stream>>>(sdesc, rw3, rb3, r3, 192, 1);
    hipMemsetAsync(slab, 0, (size_t)8192 * 384 * 4, stream);
    cgemm_cl_kernel<192, 6, 6, 4, 2><<<dim3(32, 2, 6), 256, 0, stream>>>(
        w3h, w3l, a2, r3, slab, 384, 8192, 1728, 864, 2);
    pack_cl_kernel<<<27648, 256, 0, stream>>>(slab, a3u, B, 4, 4, 384);

    // ---- Layer 4: CondConv 384->256 -> slab [B][4][4][256] ----
    wsplit_cl_kernel<<<10368, 256, 0, stream>>>(cw4, w4h, w4l, 2654208, 384);
    stats_cl_kernel<<<B, 384, 0, stream>>>(a3u, sdesc, 6, 6, 384, 0);
    routing_kernel<<<B, 64, 0, stream>>>(sdesc, cr4w, cr4b, r4, 384, 0);
    hipMemsetAsync(slab, 0, (size_t)8192 * 256 * 4, stream);
    cgemm_cl_kernel<384, 6, 6, 4, 2><<<dim3(32, 1, 12), 256, 0, stream>>>(
        w4h, w4l, a3u, r4, slab, 256, 8192, 3456, 864, 4);
    pack_cl_kernel<<<18432, 256, 0, stream>>>(slab, a4, B, 4, 4, 256);

    // ---- Layer 5: CondConv 256->256 -> slab [B][4][4][256] ----
    wsplit_cl_kernel<<<6912, 256, 0, stream>>>(cw5, w5h, w5l, 1769472, 256);
    stats_cl_kernel<<<B, 256, 0, stream>>>(a4, sdesc, 6, 6, 256, 0);
    routing_kernel<<<B, 64, 0, stream>>>(sdesc, cr5w, cr5b, r5, 256, 0);
    hipMemsetAsync(slab, 0, (size_t)8192 * 256 * 4, stream);
    cgemm_cl_kernel<256, 6, 6, 4, 2><<<dim3(32, 1, 12), 256, 0, stream>>>(
        w5h, w5l, a4, r5, slab, 256, 8192, 2304, 576, 4);

    // ---- relu + pool + flatten -> packed hT [512][1024] ----
    pool_flatten_cl_kernel<<<2048, 256, 0, stream>>>(slab, hTpk);

    // ---- FC1: 1024 -> 4096 ----
    wsplit_kernel<<<16384, 256, 0, stream>>>(fw1, f1h, f1l, 4194304, 1024, 1024);
    hipMemsetAsync(slab, 0, (size_t)4096 * 512 * 4, stream);
    mgemm_kernel<1, 0><<<dim3(4, 32, 8), 256, 0, stream>>>(
        f1h, f1l, hTpk, fb1, slab, 4096, 512, 1024, 128);
    tp_pack_kernel<<<dim3(128, 16), 256, 0, stream>>>(slab, f1pkT, 4096, 512);

    // ---- FC2: 4096 -> 4096 ----
    wsplit_kernel<<<65536, 256, 0, stream>>>(fw2, f2h, f2l, 16777216, 4096, 4096);
    hipMemsetAsync(slab, 0, (size_t)4096 * 512 * 4, stream);
    mgemm_kernel<1, 0><<<dim3(4, 32, 8), 256, 0, stream>>>(
        f2h, f2l, f1pkT, fb2, slab, 4096, 512, 4096, 512);
    tp_pack_kernel<<<dim3(128, 16), 256, 0, stream>>>(slab, f2pkT, 4096, 512);

    // ---- FC3: 4096 -> 100 -> d_out [512, 100] ----
    wsplit_kernel<<<1600, 256, 0, stream>>>(fw3, f3h, f3l, 409600, 4096, 4096);
    hipMemsetAsync(out, 0, (size_t)512 * 100 * 4, stream);
    mgemm_kernel<1, 1><<<dim3(4, 1, 32), 256, 0, stream>>>(
        f3h, f3l, f2pkT, fb3, out, 100, 512, 4096, 128);
}

// Round 7
// 2575.704 us; speedup vs baseline: 1.0236x; 1.0236x over previous
//
#include <hip/hip_runtime.h>
#include <math.h>

// ---------------------------------------------------------------------------
// DyRes/CondConv AlexNet forward. R13 (resubmit; prior round was an infra
// container failure, no bench signal). R13 = R10 base + expert-inner conv
// GEMM: k-outer/expert-inner so B (expert-invariant) is staged to LDS packed
// ONCE per K-step (pure copy) and its fragments read ONCE into 32 held
// VGPRs; each expert phase stages/reads only A + 48 MFMA. Expert fold via
// telescoped scales (sv0=r0-r1, sv1=r1-r2, sv2=r2; acc reset at step end).
// LDS/K-step: 288->192 KB (ceiling 30%->45% MfmaUtil); B global traffic /3.
// L1 conv, FC mgemm, elementwise kernels, workspace: exact R10.
// ---------------------------------------------------------------------------

typedef unsigned short u16;
typedef unsigned int u32;
typedef short bf16x8 __attribute__((ext_vector_type(8)));
typedef float f32x4 __attribute__((ext_vector_type(4)));

__device__ __forceinline__ u16 bf16_rne(float f) {
    u32 u = __float_as_uint(f);
    return (u16)((u + 0x7fffu + ((u >> 16) & 1u)) >> 16);
}
__device__ __forceinline__ u32 packsplit(float v) {
    u16 h = bf16_rne(v);
    float hf = __uint_as_float((u32)h << 16);
    u16 l = bf16_rne(v - hf);
    return ((u32)h << 16) | l;
}
__device__ __forceinline__ float unpackf(u32 p) {
    return __uint_as_float(p & 0xffff0000u) + __uint_as_float(p << 16);
}
__device__ __forceinline__ int xcd_swz(int bid, int n) {
    if ((n & 7) != 0) return bid;
    int cpx = n >> 3;
    return (bid & 7) * cpx + (bid >> 3);
}

// fp32 weights -> K-padded bf16 hi/lo planes, source k-order (ci,kh,kw)
__global__ __launch_bounds__(256)
void wsplit_kernel(const float* __restrict__ W, u16* __restrict__ whi,
                   u16* __restrict__ wlo, int total, int Kper, int Kpad)
{
    int idx = blockIdx.x * 256 + threadIdx.x;
    if (idx >= total) return;
    int r = idx / Kpad, k = idx - r * Kpad;
    float v = (k < Kper) ? W[(size_t)r * Kper + k] : 0.f;
    u16 h = bf16_rne(v);
    whi[idx] = h;
    wlo[idx] = bf16_rne(v - __uint_as_float((u32)h << 16));
}

// fp32 weights -> bf16 hi/lo planes with k-order permuted to (kh,kw,ci)
__global__ __launch_bounds__(256)
void wsplit_cl_kernel(const float* __restrict__ W, u16* __restrict__ whi,
                      u16* __restrict__ wlo, int total, int Ci)
{
    int idx = blockIdx.x * 256 + threadIdx.x;
    if (idx >= total) return;
    int Kper = 9 * Ci;
    int r = idx / Kper, kp = idx - r * Kper;
    int cell = kp / Ci, ci = kp - cell * Ci;
    float v = W[(size_t)r * Kper + ci * 9 + cell];
    u16 h = bf16_rne(v);
    whi[idx] = h;
    wlo[idx] = bf16_rne(v - __uint_as_float((u32)h << 16));
}

// stats over fp32 [B][C][HW] (layer-1 input only)
__global__ __launch_bounds__(64)
void stats_kernel(const float* __restrict__ actv, float* __restrict__ s,
                  int C, int HW, int use_std)
{
    int idx = blockIdx.x;
    size_t base = (size_t)idx * HW;
    int lane = threadIdx.x;
    float sum = 0.f, sq = 0.f;
    const float* p = actv + base;
    for (int i = lane; i < HW; i += 64) { float v = p[i]; sum += v; sq += v * v; }
#pragma unroll
    for (int off = 32; off > 0; off >>= 1) {
        sum += __shfl_down(sum, off);
        sq  += __shfl_down(sq, off);
    }
    if (lane == 0) {
        float inv = 1.f / (float)HW;
        float mean = sum * inv;
        float var = sq * inv - mean * mean;
        float outv = mean;
        if (use_std) outv += sqrtf(fmaxf(var, 0.f));
        s[idx] = outv;
    }
}

// stats over packed channels-last halo'd act [B][H2][W2][C]; block=C, grid=B
__global__ __launch_bounds__(384)
void stats_cl_kernel(const u32* __restrict__ act, float* __restrict__ s,
                     int H2, int W2, int C, int use_std)
{
    int b = blockIdx.x, c = threadIdx.x;
    int Hin = H2 - 2, Win = W2 - 2;
    float sum = 0.f, sq = 0.f;
    for (int h = 0; h < Hin; ++h)
        for (int w = 0; w < Win; ++w) {
            float v = unpackf(act[(((size_t)b * H2 + h + 1) * W2 + w + 1) * C + c]);
            sum += v; sq += v * v;
        }
    float inv = 1.f / (float)(Hin * Win);
    float mean = sum * inv;
    float var = sq * inv - mean * mean;
    float outv = mean;
    if (use_std) outv += sqrtf(fmaxf(var, 0.f));
    s[b * C + c] = outv;
}

__global__ __launch_bounds__(64)
void routing_kernel(const float* __restrict__ s, const float* __restrict__ rw,
                    const float* __restrict__ rb, float* __restrict__ r,
                    int C, int softmax_mode)
{
    int b = blockIdx.x;
    int lane = threadIdx.x;
    float d0 = 0.f, d1 = 0.f, d2 = 0.f;
    for (int c = lane; c < C; c += 64) {
        float sv = s[b * C + c];
        d0 += sv * rw[c];
        d1 += sv * rw[C + c];
        d2 += sv * rw[2 * C + c];
    }
#pragma unroll
    for (int off = 32; off > 0; off >>= 1) {
        d0 += __shfl_down(d0, off);
        d1 += __shfl_down(d1, off);
        d2 += __shfl_down(d2, off);
    }
    if (lane == 0) {
        d0 += rb[0]; d1 += rb[1]; d2 += rb[2];
        if (softmax_mode) {
            float mx = fmaxf(d0, fmaxf(d1, d2));
            float e0 = expf(d0 - mx), e1 = expf(d1 - mx), e2 = expf(d2 - mx);
            float inv = 1.f / (e0 + e1 + e2);
            r[b * 3 + 0] = e0 * inv;
            r[b * 3 + 1] = e1 * inv;
            r[b * 3 + 2] = e2 * inv;
        } else {
            r[b * 3 + 0] = 1.f / (1.f + expf(-d0));
            r[b * 3 + 1] = 1.f / (1.f + expf(-d1));
            r[b * 3 + 2] = 1.f / (1.f + expf(-d2));
        }
    }
}

// ---------------------------------------------------------------------------
// Channels-last expert-inner conv GEMM (L2-L5). Tile 128Mx128N, BK=32,
// 4 waves (2x2), wave tile 64x64. z splits K only (kq0 = bz*Kchunk).
// Per K-step: stage B packed u32 ONCE (pure copy) + read B-frags ONCE into
// 32 held VGPRs; 3 expert phases each {stage A(e) -> barrier -> 48 MFMA}.
// Telescoped expert fold per phase; acc reset per K-step.
// Pipeline: STORE(prefetched regs) -> issue next loads -> {lgkmcnt(0);
// s_barrier} (no vmcnt drain) -> compute. A dbuf per phase, B dbuf per step.
// Epilogue: plain store if gridDim.z==1 else atomicAdd (Cout pre-zeroed).
// Output transposed: C[n*M + m] (= [B][OH][OW][Co] channels-last fp32).
// ---------------------------------------------------------------------------
template<int CI, int H2, int W2, int LGS, int LGOW>
__global__ __launch_bounds__(256, 2)
void cgemm_cl_kernel(const u16* __restrict__ Whi, const u16* __restrict__ Wlo,
                     const u32* __restrict__ Bpk, const float* __restrict__ rptr,
                     float* __restrict__ Cout, int M, int N, int Kper, int Kchunk)
{
    __shared__ __align__(16) u16 Ah[2][128 * 40], Al[2][128 * 40]; // 40 KB
    __shared__ __align__(16) u32 Bp[2][128 * 36];                  // 36 KB
    const int tid = threadIdx.x;
    const int bx = xcd_swz(blockIdx.x, gridDim.x);
    const int n0 = bx << 7, m0 = blockIdx.y << 7;
    const int kq0 = blockIdx.z * Kchunk;

    // staging coords
    const int rowA = tid >> 1, kh16 = (tid & 1) << 4;   // A: 2 thr/row
    const int nB = tid & 127, kOff = (tid >> 7) << 4;   // B: 16 u32/thread

    // n-side conv coords (k-independent)
    const int nn = n0 + nB;
    const int bB = nn >> LGS;
    const int sidx = nn & ((1 << LGS) - 1);
    const int oh = sidx >> LGOW, ow = sidx & ((1 << LGOW) - 1);
    const long nBase = ((long)(bB * H2 + oh) * W2 + ow) * CI;

    const int lane = tid & 63, wv = tid >> 6;
    const int lm = lane & 15, qd = lane >> 4;
    const int wm = (wv & 1) << 6, wn = (wv >> 1) << 6;

    // telescoped expert scales per ni column
    float sv0[4], sv1[4], sv2[4];
#pragma unroll
    for (int ni = 0; ni < 4; ++ni) {
        int n = n0 + wn + ni * 16 + lm;
        int b = n >> LGS;
        float r0v = rptr[b * 3 + 0];
        float r1v = rptr[b * 3 + 1];
        float r2v = rptr[b * 3 + 2];
        sv0[ni] = r0v - r1v;
        sv1[ni] = r1v - r2v;
        sv2[ni] = r2v;
    }

    f32x4 acc[4][4], accS[4][4];
#pragma unroll
    for (int i = 0; i < 4; ++i)
#pragma unroll
        for (int j = 0; j < 4; ++j) {
            acc[i][j]  = (f32x4){0.f, 0.f, 0.f, 0.f};
            accS[i][j] = (f32x4){0.f, 0.f, 0.f, 0.f};
        }

    const int mg = m0 + rowA;
    const int nkz = Kchunk >> 5;
    const int kEnd = kq0 + Kchunk;

    // prefetch regs
    uint4 pA0, pA1, pA2, pA3;        // A phase (hi x2, lo x2)
    uint4 pQ0, pQ1, pQ2, pQ3;        // B k-step (packed u32 x16)
    uint4 pBF[8];                    // held B fragments (packed), 1 k-step

    // A load cursor (phase whose data loads next)
    int eL = 0, kL = kq0;
    auto LOAD_A = [&]() {
        size_t aOff = ((size_t)(eL * M + mg)) * Kper + kL + kh16;
        const u16* hp = Whi + aOff;
        const u16* lp = Wlo + aOff;
        pA0 = *(const uint4*)hp; pA1 = *(const uint4*)(hp + 8);
        pA2 = *(const uint4*)lp; pA3 = *(const uint4*)(lp + 8);
        if (++eL == 3) { eL = 0; kL += 32; }
    };
    auto LOAD_B = [&](int kbase) {
        int k = kbase + kOff;
        int cell = k / CI;              // CI constexpr -> folded
        int ci0 = k - cell * CI;
        int kh = (cell * 11) >> 5;
        int kw = cell - kh * 3;
        const u32* bp = Bpk + (nBase + (long)((kh * W2 + kw) * CI + ci0));
        pQ0 = *(const uint4*)bp;
        pQ1 = *(const uint4*)(bp + 4);
        pQ2 = *(const uint4*)(bp + 8);
        pQ3 = *(const uint4*)(bp + 12);
    };
    auto STORE_A = [&](int buf) {
        *(uint4*)(&Ah[buf][rowA * 40 + kh16])     = pA0;
        *(uint4*)(&Ah[buf][rowA * 40 + kh16 + 8]) = pA1;
        *(uint4*)(&Al[buf][rowA * 40 + kh16])     = pA2;
        *(uint4*)(&Al[buf][rowA * 40 + kh16 + 8]) = pA3;
    };
    auto STORE_B = [&](int bb) {
        u32* bp = &Bp[bb][nB * 36 + kOff];
        *(uint4*)(bp)      = pQ0;
        *(uint4*)(bp + 4)  = pQ1;
        *(uint4*)(bp + 8)  = pQ2;
        *(uint4*)(bp + 12) = pQ3;
    };
    auto READ_BF = [&](int bb) {
#pragma unroll
        for (int ni = 0; ni < 4; ++ni) {
            const u32* bp = &Bp[bb][(wn + ni * 16 + lm) * 36 + qd * 8];
            pBF[2 * ni]     = *(const uint4*)bp;
            pBF[2 * ni + 1] = *(const uint4*)(bp + 4);
        }
    };
    auto COMPUTE = [&](int buf) {
        bf16x8 ah[4], al[4];
#pragma unroll
        for (int mi = 0; mi < 4; ++mi) {
            int row = wm + mi * 16 + lm;
            ah[mi] = *(const bf16x8*)(&Ah[buf][row * 40 + qd * 8]);
            al[mi] = *(const bf16x8*)(&Al[buf][row * 40 + qd * 8]);
        }
        __builtin_amdgcn_s_setprio(1);
#pragma unroll
        for (int ni = 0; ni < 4; ++ni) {
            uint4 p0 = pBF[2 * ni], p1 = pBF[2 * ni + 1];
            union { u32 w[4]; bf16x8 v; } bh, bl;
            bh.w[0] = (p0.x >> 16) | (p0.y & 0xffff0000u);
            bl.w[0] = (p0.x & 0xffffu) | (p0.y << 16);
            bh.w[1] = (p0.z >> 16) | (p0.w & 0xffff0000u);
            bl.w[1] = (p0.z & 0xffffu) | (p0.w << 16);
            bh.w[2] = (p1.x >> 16) | (p1.y & 0xffff0000u);
            bl.w[2] = (p1.x & 0xffffu) | (p1.y << 16);
            bh.w[3] = (p1.z >> 16) | (p1.w & 0xffff0000u);
            bl.w[3] = (p1.z & 0xffffu) | (p1.w << 16);
#pragma unroll
            for (int mi = 0; mi < 4; ++mi) {
                f32x4 c = acc[mi][ni];
                c = __builtin_amdgcn_mfma_f32_16x16x32_bf16(al[mi], bh.v, c, 0, 0, 0);
                c = __builtin_amdgcn_mfma_f32_16x16x32_bf16(ah[mi], bl.v, c, 0, 0, 0);
                c = __builtin_amdgcn_mfma_f32_16x16x32_bf16(ah[mi], bh.v, c, 0, 0, 0);
                acc[mi][ni] = c;
            }
        }
        __builtin_amdgcn_s_setprio(0);
    };

    // ---- prologue: A for phase (e0,k0), B for k0 ----
    LOAD_A();
    LOAD_B(kq0);
    int kB = kq0 + 32;
    int buf = 0, bbuf = 0;

    for (int t = 0; t < nkz; ++t) {
        // ---- phase e=0: stage A(e0) + B(k), read B-frags, compute ----
        STORE_A(buf);
        STORE_B(bbuf);
        LOAD_A();                                 // for (t,e1) - always exists
        asm volatile("s_waitcnt lgkmcnt(0)\n\ts_barrier" ::: "memory");
        READ_BF(bbuf);
        COMPUTE(buf);
#pragma unroll
        for (int mi = 0; mi < 4; ++mi)
#pragma unroll
            for (int ni = 0; ni < 4; ++ni)
#pragma unroll
                for (int c = 0; c < 4; ++c)
                    accS[mi][ni][c] += acc[mi][ni][c] * sv0[ni];
        buf ^= 1;

        // ---- phase e=1 ----
        STORE_A(buf);
        LOAD_A();                                 // for (t,e2) - always exists
        if (kB < kEnd) { LOAD_B(kB); kB += 32; }  // next k-step's B
        asm volatile("s_waitcnt lgkmcnt(0)\n\ts_barrier" ::: "memory");
        COMPUTE(buf);
#pragma unroll
        for (int mi = 0; mi < 4; ++mi)
#pragma unroll
            for (int ni = 0; ni < 4; ++ni)
#pragma unroll
                for (int c = 0; c < 4; ++c)
                    accS[mi][ni][c] += acc[mi][ni][c] * sv1[ni];
        buf ^= 1;

        // ---- phase e=2 ----
        STORE_A(buf);
        if (t + 1 < nkz) LOAD_A();                // for (t+1,e0)
        asm volatile("s_waitcnt lgkmcnt(0)\n\ts_barrier" ::: "memory");
        COMPUTE(buf);
#pragma unroll
        for (int mi = 0; mi < 4; ++mi)
#pragma unroll
            for (int ni = 0; ni < 4; ++ni) {
#pragma unroll
                for (int c = 0; c < 4; ++c)
                    accS[mi][ni][c] += acc[mi][ni][c] * sv2[ni];
                acc[mi][ni] = (f32x4){0.f, 0.f, 0.f, 0.f};  // step reset
            }
        buf ^= 1;
        bbuf ^= 1;
    }

    // ---- epilogue: plain store (z==1) or atomicAdd (split-K) ----
    const bool atom = (gridDim.z > 1);
#pragma unroll
    for (int ni = 0; ni < 4; ++ni) {
        int n = n0 + wn + ni * 16 + lm;
#pragma unroll
        for (int mi = 0; mi < 4; ++mi)
#pragma unroll
            for (int r = 0; r < 4; ++r) {
                int m = m0 + wm + mi * 16 + qd * 4 + r;
                if (m >= M) continue;
                float v = accS[mi][ni][r];
                if (atom) atomicAdd(&Cout[(size_t)n * M + m], v);
                else      Cout[(size_t)n * M + m] = v;
            }
    }
}

// ---------------------------------------------------------------------------
// Layer-1 conv GEMM (Ci=3, stride 2): gather path, transposed output.
// ---------------------------------------------------------------------------
__global__ __launch_bounds__(256, 2)
void cgemm_l1_kernel(const u16* __restrict__ Whi, const u16* __restrict__ Wlo,
                     const u32* __restrict__ Bpk, const float* __restrict__ rptr,
                     float* __restrict__ Cout, int M, int N)
{
    __shared__ __align__(16) u16 Ah[2][128 * 40], Al[2][128 * 40];
    __shared__ __align__(16) u16 Bh[2][128 * 40], Bl[2][128 * 40];
    const int tid = threadIdx.x;
    const int bx = xcd_swz(blockIdx.x, gridDim.x);
    const int n0 = bx << 7;
    const int Kper = 27, Kpad = 32;
    const int H = 32, W = 32;

    const int rowA = tid >> 1, kh16 = (tid & 1) << 4;
    const int nB = tid & 127, kOff = (tid >> 7) << 4;

    const int nn = n0 + nB;
    const int bB = nn >> 8;
    const int sidx = nn & 255;
    const int ohs = (sidx >> 4) * 2 - 1;
    const int ows = (sidx & 15) * 2 - 1;
    const long nBase = (long)bB * 3072 + (long)ohs * W + ows;

    const int lane = tid & 63, wv = tid >> 6;
    const int lm = lane & 15, qd = lane >> 4;
    const int wm = (wv & 1) << 6, wn = (wv >> 1) << 6;

    float rsv[3][4];
#pragma unroll
    for (int ni = 0; ni < 4; ++ni) {
        int n = n0 + wn + ni * 16 + lm;
        int b = n >> 8;
#pragma unroll
        for (int e = 0; e < 3; ++e) rsv[e][ni] = rptr[b * 3 + e];
    }

    f32x4 acc[4][4], accS[4][4];
#pragma unroll
    for (int i = 0; i < 4; ++i)
#pragma unroll
        for (int j = 0; j < 4; ++j) {
            acc[i][j]  = (f32x4){0.f, 0.f, 0.f, 0.f};
            accS[i][j] = (f32x4){0.f, 0.f, 0.f, 0.f};
        }

    const int mg = rowA;
    int eL = 0;
    uint4 pA0, pA1, pA2, pA3;
    u32 pB[16];

    auto LOAD = [&]() {
        size_t aOff = ((size_t)(eL * M + mg)) * Kpad + kh16;
        const u16* hp = Whi + aOff;
        const u16* lp = Wlo + aOff;
        pA0 = *(const uint4*)hp; pA1 = *(const uint4*)(hp + 8);
        pA2 = *(const uint4*)lp; pA3 = *(const uint4*)(lp + 8);
#pragma unroll
        for (int j = 0; j < 16; ++j) {
            int k = kOff + j;
            int ci = (int)((unsigned)k / 9u);
            int r9 = k - ci * 9;
            int kh = (int)(((unsigned)r9 * 11u) >> 5);
            int kw = r9 - kh * 3;
            int ih = ohs + kh, iw = ows + kw;
            u32 p = 0;
            if (k < Kper && (unsigned)ih < (unsigned)H && (unsigned)iw < (unsigned)W)
                p = Bpk[nBase + (long)ci * 1024 + kh * W + kw];
            pB[j] = p;
        }
    };
    auto STORE = [&](int buf) {
        *(uint4*)(&Ah[buf][rowA * 40 + kh16])     = pA0;
        *(uint4*)(&Ah[buf][rowA * 40 + kh16 + 8]) = pA1;
        *(uint4*)(&Al[buf][rowA * 40 + kh16])     = pA2;
        *(uint4*)(&Al[buf][rowA * 40 + kh16 + 8]) = pA3;
        u32 hw[8], lw[8];
#pragma unroll
        for (int j = 0; j < 8; ++j) {
            u32 p0 = pB[2 * j], p1 = pB[2 * j + 1];
            hw[j] = (p0 >> 16) | (p1 & 0xffff0000u);
            lw[j] = (p0 & 0xffffu) | (p1 << 16);
        }
        *(uint4*)(&Bh[buf][nB * 40 + kOff])     = make_uint4(hw[0], hw[1], hw[2], hw[3]);
        *(uint4*)(&Bh[buf][nB * 40 + kOff + 8]) = make_uint4(hw[4], hw[5], hw[6], hw[7]);
        *(uint4*)(&Bl[buf][nB * 40 + kOff])     = make_uint4(lw[0], lw[1], lw[2], lw[3]);
        *(uint4*)(&Bl[buf][nB * 40 + kOff + 8]) = make_uint4(lw[4], lw[5], lw[6], lw[7]);
    };
    auto COMPUTE = [&](int buf) {
        bf16x8 ah[4], al[4];
#pragma unroll
        for (int mi = 0; mi < 4; ++mi) {
            int row = wm + mi * 16 + lm;
            ah[mi] = *(const bf16x8*)(&Ah[buf][row * 40 + qd * 8]);
            al[mi] = *(const bf16x8*)(&Al[buf][row * 40 + qd * 8]);
        }
        __builtin_amdgcn_s_setprio(1);
#pragma unroll
        for (int ni = 0; ni < 4; ++ni) {
            int row = wn + ni * 16 + lm;
            bf16x8 bh = *(const bf16x8*)(&Bh[buf][row * 40 + qd * 8]);
            bf16x8 bl = *(const bf16x8*)(&Bl[buf][row * 40 + qd * 8]);
#pragma unroll
            for (int mi = 0; mi < 4; ++mi) {
                f32x4 c = acc[mi][ni];
                c = __builtin_amdgcn_mfma_f32_16x16x32_bf16(al[mi], bh, c, 0, 0, 0);
                c = __builtin_amdgcn_mfma_f32_16x16x32_bf16(ah[mi], bl, c, 0, 0, 0);
                c = __builtin_amdgcn_mfma_f32_16x16x32_bf16(ah[mi], bh, c, 0, 0, 0);
                acc[mi][ni] = c;
            }
        }
        __builtin_amdgcn_s_setprio(0);
    };

    LOAD(); ++eL;
    int buf = 0;
#pragma unroll
    for (int e = 0; e < 3; ++e) {
        STORE(buf);
        if (e < 2) { LOAD(); ++eL; }
        asm volatile("s_waitcnt lgkmcnt(0)\n\ts_barrier" ::: "memory");
        COMPUTE(buf);
        buf ^= 1;
#pragma unroll
        for (int mi = 0; mi < 4; ++mi)
#pragma unroll
            for (int ni = 0; ni < 4; ++ni) {
                accS[mi][ni] += acc[mi][ni] * rsv[e][ni];
                acc[mi][ni] = (f32x4){0.f, 0.f, 0.f, 0.f};
            }
    }

#pragma unroll
    for (int ni = 0; ni < 4; ++ni) {
        int n = n0 + wn + ni * 16 + lm;
#pragma unroll
        for (int mi = 0; mi < 4; ++mi)
#pragma unroll
            for (int r = 0; r < 4; ++r) {
                int m = wm + mi * 16 + qd * 4 + r;
                if (m >= M) continue;
                Cout[(size_t)n * M + m] = accS[mi][ni][r];
            }
    }
}

// ---------------------------------------------------------------------------
// FC GEMM: 128Mx128N tile, BK=32, split-K atomics. (proven R7 form)
// ---------------------------------------------------------------------------
template<int BIAS, int TROUT>
__global__ __launch_bounds__(256)
void mgemm_kernel(const u16* __restrict__ Whi, const u16* __restrict__ Wlo,
                  const u32* __restrict__ Bpk, const float* __restrict__ bias,
                  float* __restrict__ Cout,
                  int M, int N, int Kpad, int Kchunk)
{
    __shared__ __align__(16) u16 Ah[128 * 40], Al[128 * 40];
    __shared__ __align__(16) u32 Bp[128 * 36];
    const int tid = threadIdx.x;
    const int n0 = blockIdx.x << 7, m0 = blockIdx.y << 7;
    const int bz = blockIdx.z;
    const int kq0 = bz * Kchunk;

    const int rowA = tid >> 1, kh16 = (tid & 1) << 4;
    const int nB = tid & 127, kOff = (tid >> 7) << 4;

    const int lane = tid & 63, wv = tid >> 6;
    const int lm = lane & 15, qd = lane >> 4;
    const int wm = (wv & 1) << 6, wn = (wv >> 1) << 6;

    f32x4 acc[4][4];
#pragma unroll
    for (int i = 0; i < 4; ++i)
#pragma unroll
        for (int j = 0; j < 4; ++j)
            acc[i][j] = (f32x4){0.f, 0.f, 0.f, 0.f};

    for (int kq = kq0; kq < kq0 + Kchunk; kq += 32) {
        {
            int mg = m0 + rowA;
            uint4 h0 = {0,0,0,0}, h1 = {0,0,0,0}, l0 = {0,0,0,0}, l1 = {0,0,0,0};
            if (mg < M) {
                const u16* hp = Whi + (size_t)mg * Kpad + kq + kh16;
                const u16* lp = Wlo + (size_t)mg * Kpad + kq + kh16;
                h0 = *(const uint4*)hp; h1 = *(const uint4*)(hp + 8);
                l0 = *(const uint4*)lp; l1 = *(const uint4*)(lp + 8);
            }
            *(uint4*)(&Ah[rowA * 40 + kh16])     = h0;
            *(uint4*)(&Ah[rowA * 40 + kh16 + 8]) = h1;
            *(uint4*)(&Al[rowA * 40 + kh16])     = l0;
            *(uint4*)(&Al[rowA * 40 + kh16 + 8]) = l1;
        }
        {
            const u32* bp = Bpk + (size_t)(n0 + nB) * Kpad + kq + kOff;
            uint4 q0 = *(const uint4*)bp;
            uint4 q1 = *(const uint4*)(bp + 4);
            uint4 q2 = *(const uint4*)(bp + 8);
            uint4 q3 = *(const uint4*)(bp + 12);
            *(uint4*)(&Bp[nB * 36 + kOff])      = q0;
            *(uint4*)(&Bp[nB * 36 + kOff + 4])  = q1;
            *(uint4*)(&Bp[nB * 36 + kOff + 8])  = q2;
            *(uint4*)(&Bp[nB * 36 + kOff + 12]) = q3;
        }
        __syncthreads();
        {
            bf16x8 ah[4], al[4];
#pragma unroll
            for (int mi = 0; mi < 4; ++mi) {
                int row = wm + mi * 16 + lm;
                ah[mi] = *(const bf16x8*)(&Ah[row * 40 + qd * 8]);
                al[mi] = *(const bf16x8*)(&Al[row * 40 + qd * 8]);
            }
#pragma unroll
            for (int ni = 0; ni < 4; ++ni) {
                int row = wn + ni * 16 + lm;
                const u32* bp = &Bp[row * 36 + qd * 8];
                uint4 p0 = *(const uint4*)bp;
                uint4 p1 = *(const uint4*)(bp + 4);
                union { u32 w[4]; bf16x8 v; } bh, bl;
                bh.w[0] = (p0.x >> 16) | (p0.y & 0xffff0000u);
                bl.w[0] = (p0.x & 0xffffu) | (p0.y << 16);
                bh.w[1] = (p0.z >> 16) | (p0.w & 0xffff0000u);
                bl.w[1] = (p0.z & 0xffffu) | (p0.w << 16);
                bh.w[2] = (p1.x >> 16) | (p1.y & 0xffff0000u);
                bl.w[2] = (p1.x & 0xffffu) | (p1.y << 16);
                bh.w[3] = (p1.z >> 16) | (p1.w & 0xffff0000u);
                bl.w[3] = (p1.z & 0xffffu) | (p1.w << 16);
#pragma unroll
                for (int mi = 0; mi < 4; ++mi) {
                    f32x4 c = acc[mi][ni];
                    c = __builtin_amdgcn_mfma_f32_16x16x32_bf16(al[mi], bh.v, c, 0, 0, 0);
                    c = __builtin_amdgcn_mfma_f32_16x16x32_bf16(ah[mi], bl.v, c, 0, 0, 0);
                    c = __builtin_amdgcn_mfma_f32_16x16x32_bf16(ah[mi], bh.v, c, 0, 0, 0);
                    acc[mi][ni] = c;
                }
            }
        }
        __syncthreads();
    }

#pragma unroll
    for (int ni = 0; ni < 4; ++ni) {
        int n = n0 + wn + ni * 16 + lm;
        if (n >= N) continue;
#pragma unroll
        for (int mi = 0; mi < 4; ++mi)
#pragma unroll
            for (int r = 0; r < 4; ++r) {
                int m = m0 + wm + mi * 16 + qd * 4 + r;
                if (m >= M) continue;
                float v = acc[mi][ni][r];
                if (BIAS && bz == 0) v += bias[m];
                if (TROUT) atomicAdd(&Cout[(size_t)n * M + m], v);
                else       atomicAdd(&Cout[(size_t)m * N + n], v);
            }
    }
}

// elementwise fp32 -> packed bf16x2
__global__ __launch_bounds__(256)
void pack_kernel(const float* __restrict__ in, u32* __restrict__ outp, int count)
{
    int i = blockIdx.x * 256 + threadIdx.x;
    if (i >= count) return;
    outp[i] = packsplit(in[i]);
}

// 2x2/2 maxpool + relu: [B][Hin][Win][C] fp32 -> halo'd packed [B][OH+2][OW+2][C]
__global__ __launch_bounds__(256)
void pool_pack_cl_kernel(const float* __restrict__ in, u32* __restrict__ outp,
                         int Bn, int Hin, int Win, int C)
{
    int OH = Hin >> 1, OW = Win >> 1, H2 = OH + 2, W2 = OW + 2;
    int total = Bn * H2 * W2 * C;
    int i = blockIdx.x * 256 + threadIdx.x;
    if (i >= total) return;
    int c = i % C; int t = i / C;
    int w = t % W2; t /= W2;
    int h = t % H2; int b = t / H2;
    u32 pv = 0;
    if (h >= 1 && h <= OH && w >= 1 && w <= OW) {
        int oh = h - 1, ow = w - 1;
        const float* p = in + (((size_t)b * Hin + 2 * oh) * Win + 2 * ow) * C + c;
        size_t rs = (size_t)Win * C;
        float v = fmaxf(fmaxf(p[0], p[C]), fmaxf(p[rs], p[rs + C]));
        pv = packsplit(fmaxf(v, 0.f));
    }
    outp[i] = pv;
}

// relu (no pool): [B][Hin][Win][C] fp32 -> halo'd packed [B][Hin+2][Win+2][C]
__global__ __launch_bounds__(256)
void pack_cl_kernel(const float* __restrict__ in, u32* __restrict__ outp,
                    int Bn, int Hin, int Win, int C)
{
    int H2 = Hin + 2, W2 = Win + 2;
    int total = Bn * H2 * W2 * C;
    int i = blockIdx.x * 256 + threadIdx.x;
    if (i >= total) return;
    int c = i % C; int t = i / C;
    int w = t % W2; t /= W2;
    int h = t % H2; int b = t / H2;
    u32 pv = 0;
    if (h >= 1 && h <= Hin && w >= 1 && w <= Win) {
        float v = in[(((size_t)b * Hin + (h - 1)) * Win + (w - 1)) * C + c];
        pv = packsplit(fmaxf(v, 0.f));
    }
    outp[i] = pv;
}

// L5 out [B][4][4][256] fp32 --relu+pool--> packed hT[b][f]
__global__ __launch_bounds__(256)
void pool_flatten_cl_kernel(const float* __restrict__ in, u32* __restrict__ outp)
{
    int i = blockIdx.x * 256 + threadIdx.x;
    if (i >= 512 * 1024) return;
    int b = i >> 10;
    int f = i & 1023;
    int c = f >> 2, sp = f & 3;
    int oh = sp >> 1, ow = sp & 1;
    const float* p = in + (((size_t)b * 4 + 2 * oh) * 4 + 2 * ow) * 256 + c;
    float v = fmaxf(fmaxf(p[0], p[256]), fmaxf(p[1024], p[1024 + 256]));
    outp[i] = packsplit(fmaxf(v, 0.f));
}

// FC act: fp32 [Mt][Nt] --relu--> packed transposed [Nt][Mt]
__global__ __launch_bounds__(256)
void tp_pack_kernel(const float* __restrict__ in, u32* __restrict__ outp,
                    int Mt, int Nt)
{
    __shared__ float t[32][33];
    int tx = threadIdx.x & 31, ty = threadIdx.x >> 5;
    int mB = blockIdx.x << 5, nB = blockIdx.y << 5;
#pragma unroll
    for (int i = 0; i < 4; ++i) {
        int mm = ty + i * 8;
        t[mm][tx] = in[(size_t)(mB + mm) * Nt + nB + tx];
    }
    __syncthreads();
#pragma unroll
    for (int i = 0; i < 4; ++i) {
        int nn = ty + i * 8;
        float v = fmaxf(t[tx][nn], 0.f);
        outp[(size_t)(nB + nn) * Mt + mB + tx] = packsplit(v);
    }
}

extern "C" void kernel_launch(void* const* d_in, const int* in_sizes, int n_in,
                              void* d_out, int out_size, void* d_ws, size_t ws_size,
                              hipStream_t stream)
{
    const float* x    = (const float*)d_in[0];
    const float* dw1  = (const float*)d_in[1];
    const float* rw1  = (const float*)d_in[2];
    const float* rb1  = (const float*)d_in[3];
    const float* dw2  = (const float*)d_in[4];
    const float* rw2  = (const float*)d_in[5];
    const float* rb2  = (const float*)d_in[6];
    const float* dw3  = (const float*)d_in[7];
    const float* rw3  = (const float*)d_in[8];
    const float* rb3  = (const float*)d_in[9];
    const float* cw4  = (const float*)d_in[10];
    const float* cr4w = (const float*)d_in[11];
    const float* cr4b = (const float*)d_in[12];
    const float* cw5  = (const float*)d_in[13];
    const float* cr5w = (const float*)d_in[14];
    const float* cr5b = (const float*)d_in[15];
    const float* fw1  = (const float*)d_in[16];
    const float* fb1  = (const float*)d_in[17];
    const float* fw2  = (const float*)d_in[18];
    const float* fb2  = (const float*)d_in[19];
    const float* fw3  = (const float*)d_in[20];
    const float* fb3  = (const float*)d_in[21];
    float* out = (float*)d_out;

    // ---- workspace (float units); layout as R10 ----
    float* ws    = (float*)d_ws;
    float* r1    = ws;
    float* r2    = r1 + 1536;
    float* r3    = r2 + 1536;
    float* r4    = r3 + 1536;
    float* r5    = r4 + 1536;
    float* sdesc = ws + 8192 + 65536;
    const size_t REGION = 18874368;           // 75.5 MB region
    float* region = sdesc + 196608;
    float* slab   = region;                   // fp32 out-slab (front)
    u32*   a3u    = (u32*)(region + 4194304); // [512][6][6][384] packed u32
    u16*   regEnd = (u16*)(region + REGION);
    u32*   P1     = (u32*)(region + REGION);  // 6,291,456 u32 (25.2 MB)

    u16 *w1h = regEnd - 2*(size_t)6144,     *w1l = regEnd - (size_t)6144;
    u16 *w2h = regEnd - 2*(size_t)331776,   *w2l = regEnd - (size_t)331776;
    u16 *w3h = regEnd - 2*(size_t)1990656,  *w3l = regEnd - (size_t)1990656;
    u16 *w4h = regEnd - 2*(size_t)2654208,  *w4l = regEnd - (size_t)2654208;
    u16 *w5h = regEnd - 2*(size_t)1769472,  *w5l = regEnd - (size_t)1769472;
    u16 *f1h = regEnd - 2*(size_t)4194304,  *f1l = regEnd - (size_t)4194304;
    u16 *f2h = regEnd - 2*(size_t)16777216, *f2l = regEnd - (size_t)16777216;
    u16 *f3h = regEnd - 2*(size_t)409600,   *f3l = regEnd - (size_t)409600;

    u32* xpk   = P1;                 // [B][3][32][32]
    u32* a1    = P1;                 // [512][10][10][64]
    u32* a2    = P1;                 // [512][6][6][192]
    u32* a4    = P1;                 // [512][6][6][256]
    u32* hTpk  = P1;                 // [512][1024]
    u32* f1pkT = P1 + 1048576;
    u32* f2pkT = P1 + 3145728;

    const int B = 512;

    // ---- input pack ----
    pack_kernel<<<6144, 256, 0, stream>>>(x, xpk, 1572864);

    // ---- Layer 1: DyRes conv 3->64, s2 p1 -> slab [B][16][16][64] ----
    wsplit_kernel<<<24, 256, 0, stream>>>(dw1, w1h, w1l, 6144, 27, 32);
    stats_kernel<<<B * 3, 64, 0, stream>>>(x, sdesc, 3, 1024, 1);
    routing_kernel<<<B, 64, 0, stream>>>(sdesc, rw1, rb1, r1, 3, 1);
    cgemm_l1_kernel<<<dim3(1024, 1, 1), 256, 0, stream>>>(
        w1h, w1l, xpk, r1, slab, 64, 131072);
    pool_pack_cl_kernel<<<12800, 256, 0, stream>>>(slab, a1, B, 16, 16, 64);

    // ---- Layer 2: DyRes conv 64->192 -> slab [B][8][8][192] ----
    wsplit_cl_kernel<<<1296, 256, 0, stream>>>(dw2, w2h, w2l, 331776, 64);
    stats_cl_kernel<<<B, 64, 0, stream>>>(a1, sdesc, 10, 10, 64, 1);
    routing_kernel<<<B, 64, 0, stream>>>(sdesc, rw2, rb2, r2, 64, 1);
    cgemm_cl_kernel<64, 10, 10, 6, 3><<<dim3(256, 2, 1), 256, 0, stream>>>(
        w2h, w2l, a1, r2, slab, 192, 32768, 576, 576);
    pool_pack_cl_kernel<<<13824, 256, 0, stream>>>(slab, a2, B, 8, 8, 192);

    // ---- Layer 3: DyRes conv 192->384 -> slab [B][4][4][384] ----
    wsplit_cl_kernel<<<7776, 256, 0, stream>>>(dw3, w3h, w3l, 1990656, 192);
    stats_cl_kernel<<<B, 192, 0, stream>>>(a2, sdesc, 6, 6, 192, 1);
    routing_kernel<<<B, 64, 0, stream>>>(sdesc, rw3, rb3, r3, 192, 1);
    hipMemsetAsync(slab, 0, (size_t)8192 * 384 * 4, stream);
    cgemm_cl_kernel<192, 6, 6, 4, 2><<<dim3(64, 3, 2), 256, 0, stream>>>(
        w3h, w3l, a2, r3, slab, 384, 8192, 1728, 864);
    pack_cl_kernel<<<27648, 256, 0, stream>>>(slab, a3u, B, 4, 4, 384);

    // ---- Layer 4: CondConv 384->256 -> slab [B][4][4][256] ----
    wsplit_cl_kernel<<<10368, 256, 0, stream>>>(cw4, w4h, w4l, 2654208, 384);
    stats_cl_kernel<<<B, 384, 0, stream>>>(a3u, sdesc, 6, 6, 384, 0);
    routing_kernel<<<B, 64, 0, stream>>>(sdesc, cr4w, cr4b, r4, 384, 0);
    hipMemsetAsync(slab, 0, (size_t)8192 * 256 * 4, stream);
    cgemm_cl_kernel<384, 6, 6, 4, 2><<<dim3(64, 2, 4), 256, 0, stream>>>(
        w4h, w4l, a3u, r4, slab, 256, 8192, 3456, 864);
    pack_cl_kernel<<<18432, 256, 0, stream>>>(slab, a4, B, 4, 4, 256);

    // ---- Layer 5: CondConv 256->256 -> slab [B][4][4][256] ----
    wsplit_cl_kernel<<<6912, 256, 0, stream>>>(cw5, w5h, w5l, 1769472, 256);
    stats_cl_kernel<<<B, 256, 0, stream>>>(a4, sdesc, 6, 6, 256, 0);
    routing_kernel<<<B, 64, 0, stream>>>(sdesc, cr5w, cr5b, r5, 256, 0);
    hipMemsetAsync(slab, 0, (size_t)8192 * 256 * 4, stream);
    cgemm_cl_kernel<256, 6, 6, 4, 2><<<dim3(64, 2, 4), 256, 0, stream>>>(
        w5h, w5l, a4, r5, slab, 256, 8192, 2304, 576);

    // ---- relu + pool + flatten -> packed hT [512][1024] ----
    pool_flatten_cl_kernel<<<2048, 256, 0, stream>>>(slab, hTpk);

    // ---- FC1: 1024 -> 4096 ----
    wsplit_kernel<<<16384, 256, 0, stream>>>(fw1, f1h, f1l, 4194304, 1024, 1024);
    hipMemsetAsync(slab, 0, (size_t)4096 * 512 * 4, stream);
    mgemm_kernel<1, 0><<<dim3(4, 32, 8), 256, 0, stream>>>(
        f1h, f1l, hTpk, fb1, slab, 4096, 512, 1024, 128);
    tp_pack_kernel<<<dim3(128, 16), 256, 0, stream>>>(slab, f1pkT, 4096, 512);

    // ---- FC2: 4096 -> 4096 ----
    wsplit_kernel<<<65536, 256, 0, stream>>>(fw2, f2h, f2l, 16777216, 4096, 4096);
    hipMemsetAsync(slab, 0, (size_t)4096 * 512 * 4, stream);
    mgemm_kernel<1, 0><<<dim3(4, 32, 8), 256, 0, stream>>>(
        f2h, f2l, f1pkT, fb2, slab, 4096, 512, 4096, 512);
    tp_pack_kernel<<<dim3(128, 16), 256, 0, stream>>>(slab, f2pkT, 4096, 512);

    // ---- FC3: 4096 -> 100 -> d_out [512, 100] ----
    wsplit_kernel<<<1600, 256, 0, stream>>>(fw3, f3h, f3l, 409600, 4096, 4096);
    hipMemsetAsync(out, 0, (size_t)512 * 100 * 4, stream);
    mgemm_kernel<1, 1><<<dim3(4, 1, 32), 256, 0, stream>>>(
        f3h, f3l, f2pkT, fb3, out, 100, 512, 4096, 128);
}

// Round 8
// 2504.958 us; speedup vs baseline: 1.0525x; 1.0282x over previous
//
#include <hip/hip_runtime.h>
#include <math.h>

// ---------------------------------------------------------------------------
// DyRes/CondConv AlexNet forward. R14 = R13 minus the register hog.
// R13 post-mortem: holding B-fragments in 32 VGPRs across all 3 expert
// phases pushed the live set past the 256/wave budget -> accS spilled to
// scratch (1 GB R+W per dispatch, 45% HBM). R14 keeps the k-outer/expert-
// inner structure (B staged packed ONCE per K-step: B global fetch /3,
// B LDS writes /3) but COMPUTE re-reads packed B-frags from LDS each phase
// (register profile = R10's proven no-spill shape). Telescoped expert fold
// (sv0=r0-r1, sv1=r1-r2, sv2=r2; acc reset per K-step).
// Also: FC mgemm now uses the proven raw-barrier double-buffered pipeline
// (reg prefetch + lgkmcnt(0)-only barrier, no vmcnt drain).
// L1 conv, elementwise kernels, workspace: exact R10.
// ---------------------------------------------------------------------------

typedef unsigned short u16;
typedef unsigned int u32;
typedef short bf16x8 __attribute__((ext_vector_type(8)));
typedef float f32x4 __attribute__((ext_vector_type(4)));

__device__ __forceinline__ u16 bf16_rne(float f) {
    u32 u = __float_as_uint(f);
    return (u16)((u + 0x7fffu + ((u >> 16) & 1u)) >> 16);
}
__device__ __forceinline__ u32 packsplit(float v) {
    u16 h = bf16_rne(v);
    float hf = __uint_as_float((u32)h << 16);
    u16 l = bf16_rne(v - hf);
    return ((u32)h << 16) | l;
}
__device__ __forceinline__ float unpackf(u32 p) {
    return __uint_as_float(p & 0xffff0000u) + __uint_as_float(p << 16);
}
__device__ __forceinline__ int xcd_swz(int bid, int n) {
    if ((n & 7) != 0) return bid;
    int cpx = n >> 3;
    return (bid & 7) * cpx + (bid >> 3);
}

// fp32 weights -> K-padded bf16 hi/lo planes, source k-order (ci,kh,kw)
__global__ __launch_bounds__(256)
void wsplit_kernel(const float* __restrict__ W, u16* __restrict__ whi,
                   u16* __restrict__ wlo, int total, int Kper, int Kpad)
{
    int idx = blockIdx.x * 256 + threadIdx.x;
    if (idx >= total) return;
    int r = idx / Kpad, k = idx - r * Kpad;
    float v = (k < Kper) ? W[(size_t)r * Kper + k] : 0.f;
    u16 h = bf16_rne(v);
    whi[idx] = h;
    wlo[idx] = bf16_rne(v - __uint_as_float((u32)h << 16));
}

// fp32 weights -> bf16 hi/lo planes with k-order permuted to (kh,kw,ci)
__global__ __launch_bounds__(256)
void wsplit_cl_kernel(const float* __restrict__ W, u16* __restrict__ whi,
                      u16* __restrict__ wlo, int total, int Ci)
{
    int idx = blockIdx.x * 256 + threadIdx.x;
    if (idx >= total) return;
    int Kper = 9 * Ci;
    int r = idx / Kper, kp = idx - r * Kper;
    int cell = kp / Ci, ci = kp - cell * Ci;
    float v = W[(size_t)r * Kper + ci * 9 + cell];
    u16 h = bf16_rne(v);
    whi[idx] = h;
    wlo[idx] = bf16_rne(v - __uint_as_float((u32)h << 16));
}

// stats over fp32 [B][C][HW] (layer-1 input only)
__global__ __launch_bounds__(64)
void stats_kernel(const float* __restrict__ actv, float* __restrict__ s,
                  int C, int HW, int use_std)
{
    int idx = blockIdx.x;
    size_t base = (size_t)idx * HW;
    int lane = threadIdx.x;
    float sum = 0.f, sq = 0.f;
    const float* p = actv + base;
    for (int i = lane; i < HW; i += 64) { float v = p[i]; sum += v; sq += v * v; }
#pragma unroll
    for (int off = 32; off > 0; off >>= 1) {
        sum += __shfl_down(sum, off);
        sq  += __shfl_down(sq, off);
    }
    if (lane == 0) {
        float inv = 1.f / (float)HW;
        float mean = sum * inv;
        float var = sq * inv - mean * mean;
        float outv = mean;
        if (use_std) outv += sqrtf(fmaxf(var, 0.f));
        s[idx] = outv;
    }
}

// stats over packed channels-last halo'd act [B][H2][W2][C]; block=C, grid=B
__global__ __launch_bounds__(384)
void stats_cl_kernel(const u32* __restrict__ act, float* __restrict__ s,
                     int H2, int W2, int C, int use_std)
{
    int b = blockIdx.x, c = threadIdx.x;
    int Hin = H2 - 2, Win = W2 - 2;
    float sum = 0.f, sq = 0.f;
    for (int h = 0; h < Hin; ++h)
        for (int w = 0; w < Win; ++w) {
            float v = unpackf(act[(((size_t)b * H2 + h + 1) * W2 + w + 1) * C + c]);
            sum += v; sq += v * v;
        }
    float inv = 1.f / (float)(Hin * Win);
    float mean = sum * inv;
    float var = sq * inv - mean * mean;
    float outv = mean;
    if (use_std) outv += sqrtf(fmaxf(var, 0.f));
    s[b * C + c] = outv;
}

__global__ __launch_bounds__(64)
void routing_kernel(const float* __restrict__ s, const float* __restrict__ rw,
                    const float* __restrict__ rb, float* __restrict__ r,
                    int C, int softmax_mode)
{
    int b = blockIdx.x;
    int lane = threadIdx.x;
    float d0 = 0.f, d1 = 0.f, d2 = 0.f;
    for (int c = lane; c < C; c += 64) {
        float sv = s[b * C + c];
        d0 += sv * rw[c];
        d1 += sv * rw[C + c];
        d2 += sv * rw[2 * C + c];
    }
#pragma unroll
    for (int off = 32; off > 0; off >>= 1) {
        d0 += __shfl_down(d0, off);
        d1 += __shfl_down(d1, off);
        d2 += __shfl_down(d2, off);
    }
    if (lane == 0) {
        d0 += rb[0]; d1 += rb[1]; d2 += rb[2];
        if (softmax_mode) {
            float mx = fmaxf(d0, fmaxf(d1, d2));
            float e0 = expf(d0 - mx), e1 = expf(d1 - mx), e2 = expf(d2 - mx);
            float inv = 1.f / (e0 + e1 + e2);
            r[b * 3 + 0] = e0 * inv;
            r[b * 3 + 1] = e1 * inv;
            r[b * 3 + 2] = e2 * inv;
        } else {
            r[b * 3 + 0] = 1.f / (1.f + expf(-d0));
            r[b * 3 + 1] = 1.f / (1.f + expf(-d1));
            r[b * 3 + 2] = 1.f / (1.f + expf(-d2));
        }
    }
}

// ---------------------------------------------------------------------------
// Channels-last expert-inner conv GEMM (L2-L5). Tile 128Mx128N, BK=32,
// 4 waves (2x2), wave tile 64x64. z splits K only (kq0 = bz*Kchunk).
// Per K-step: stage B packed ONCE (4 uint4 writes); 3 expert phases each
// {stage A(e) -> barrier -> read A frags + read/unpack packed B frags ->
// 48 MFMA -> telescoped fold}. acc reset per K-step. No held B regs
// (R13's pBF caused scratch spill).
// Epilogue: plain store if gridDim.z==1 else atomicAdd (Cout pre-zeroed).
// Output transposed: C[n*M + m] (= [B][OH][OW][Co] channels-last fp32).
// ---------------------------------------------------------------------------
template<int CI, int H2, int W2, int LGS, int LGOW>
__global__ __launch_bounds__(256, 2)
void cgemm_cl_kernel(const u16* __restrict__ Whi, const u16* __restrict__ Wlo,
                     const u32* __restrict__ Bpk, const float* __restrict__ rptr,
                     float* __restrict__ Cout, int M, int N, int Kper, int Kchunk)
{
    __shared__ __align__(16) u16 Ah[2][128 * 40], Al[2][128 * 40]; // 40 KB
    __shared__ __align__(16) u32 Bp[2][128 * 36];                  // 36 KB
    const int tid = threadIdx.x;
    const int bx = xcd_swz(blockIdx.x, gridDim.x);
    const int n0 = bx << 7, m0 = blockIdx.y << 7;
    const int kq0 = blockIdx.z * Kchunk;

    // staging coords
    const int rowA = tid >> 1, kh16 = (tid & 1) << 4;   // A: 2 thr/row
    const int nB = tid & 127, kOff = (tid >> 7) << 4;   // B: 16 u32/thread

    // n-side conv coords (k-independent)
    const int nn = n0 + nB;
    const int bB = nn >> LGS;
    const int sidx = nn & ((1 << LGS) - 1);
    const int oh = sidx >> LGOW, ow = sidx & ((1 << LGOW) - 1);
    const long nBase = ((long)(bB * H2 + oh) * W2 + ow) * CI;

    const int lane = tid & 63, wv = tid >> 6;
    const int lm = lane & 15, qd = lane >> 4;
    const int wm = (wv & 1) << 6, wn = (wv >> 1) << 6;

    // telescoped expert scales per ni column
    float sv0[4], sv1[4], sv2[4];
#pragma unroll
    for (int ni = 0; ni < 4; ++ni) {
        int n = n0 + wn + ni * 16 + lm;
        int b = n >> LGS;
        float r0v = rptr[b * 3 + 0];
        float r1v = rptr[b * 3 + 1];
        float r2v = rptr[b * 3 + 2];
        sv0[ni] = r0v - r1v;
        sv1[ni] = r1v - r2v;
        sv2[ni] = r2v;
    }

    f32x4 acc[4][4], accS[4][4];
#pragma unroll
    for (int i = 0; i < 4; ++i)
#pragma unroll
        for (int j = 0; j < 4; ++j) {
            acc[i][j]  = (f32x4){0.f, 0.f, 0.f, 0.f};
            accS[i][j] = (f32x4){0.f, 0.f, 0.f, 0.f};
        }

    const int mg = m0 + rowA;
    const int nkz = Kchunk >> 5;
    const int kEnd = kq0 + Kchunk;

    // prefetch regs
    uint4 pA0, pA1, pA2, pA3;        // A phase (hi x2, lo x2)
    uint4 pQ0, pQ1, pQ2, pQ3;        // B k-step (packed u32 x16)

    // A load cursor (phase whose data loads next)
    int eL = 0, kL = kq0;
    auto LOAD_A = [&]() {
        size_t aOff = ((size_t)(eL * M + mg)) * Kper + kL + kh16;
        const u16* hp = Whi + aOff;
        const u16* lp = Wlo + aOff;
        pA0 = *(const uint4*)hp; pA1 = *(const uint4*)(hp + 8);
        pA2 = *(const uint4*)lp; pA3 = *(const uint4*)(lp + 8);
        if (++eL == 3) { eL = 0; kL += 32; }
    };
    auto LOAD_B = [&](int kbase) {
        int k = kbase + kOff;
        int cell = k / CI;              // CI constexpr -> folded
        int ci0 = k - cell * CI;
        int kh = (cell * 11) >> 5;
        int kw = cell - kh * 3;
        const u32* bp = Bpk + (nBase + (long)((kh * W2 + kw) * CI + ci0));
        pQ0 = *(const uint4*)bp;
        pQ1 = *(const uint4*)(bp + 4);
        pQ2 = *(const uint4*)(bp + 8);
        pQ3 = *(const uint4*)(bp + 12);
    };
    auto STORE_A = [&](int buf) {
        *(uint4*)(&Ah[buf][rowA * 40 + kh16])     = pA0;
        *(uint4*)(&Ah[buf][rowA * 40 + kh16 + 8]) = pA1;
        *(uint4*)(&Al[buf][rowA * 40 + kh16])     = pA2;
        *(uint4*)(&Al[buf][rowA * 40 + kh16 + 8]) = pA3;
    };
    auto STORE_B = [&](int bb) {
        u32* bp = &Bp[bb][nB * 36 + kOff];
        *(uint4*)(bp)      = pQ0;
        *(uint4*)(bp + 4)  = pQ1;
        *(uint4*)(bp + 8)  = pQ2;
        *(uint4*)(bp + 12) = pQ3;
    };
    auto COMPUTE = [&](int abuf, int bb) {
        bf16x8 ah[4], al[4];
#pragma unroll
        for (int mi = 0; mi < 4; ++mi) {
            int row = wm + mi * 16 + lm;
            ah[mi] = *(const bf16x8*)(&Ah[abuf][row * 40 + qd * 8]);
            al[mi] = *(const bf16x8*)(&Al[abuf][row * 40 + qd * 8]);
        }
        __builtin_amdgcn_s_setprio(1);
#pragma unroll
        for (int ni = 0; ni < 4; ++ni) {
            const u32* bp = &Bp[bb][(wn + ni * 16 + lm) * 36 + qd * 8];
            uint4 p0 = *(const uint4*)bp;
            uint4 p1 = *(const uint4*)(bp + 4);
            union { u32 w[4]; bf16x8 v; } bh, bl;
            bh.w[0] = (p0.x >> 16) | (p0.y & 0xffff0000u);
            bl.w[0] = (p0.x & 0xffffu) | (p0.y << 16);
            bh.w[1] = (p0.z >> 16) | (p0.w & 0xffff0000u);
            bl.w[1] = (p0.z & 0xffffu) | (p0.w << 16);
            bh.w[2] = (p1.x >> 16) | (p1.y & 0xffff0000u);
            bl.w[2] = (p1.x & 0xffffu) | (p1.y << 16);
            bh.w[3] = (p1.z >> 16) | (p1.w & 0xffff0000u);
            bl.w[3] = (p1.z & 0xffffu) | (p1.w << 16);
#pragma unroll
            for (int mi = 0; mi < 4; ++mi) {
                f32x4 c = acc[mi][ni];
                c = __builtin_amdgcn_mfma_f32_16x16x32_bf16(al[mi], bh.v, c, 0, 0, 0);
                c = __builtin_amdgcn_mfma_f32_16x16x32_bf16(ah[mi], bl.v, c, 0, 0, 0);
                c = __builtin_amdgcn_mfma_f32_16x16x32_bf16(ah[mi], bh.v, c, 0, 0, 0);
                acc[mi][ni] = c;
            }
        }
        __builtin_amdgcn_s_setprio(0);
    };

    // ---- prologue: A for phase (e0,k0), B for k0 ----
    LOAD_A();
    LOAD_B(kq0);
    int kB = kq0 + 32;
    int buf = 0, bbuf = 0;

    for (int t = 0; t < nkz; ++t) {
        // ---- phase e=0: stage A(e0) + B(k); compute ----
        STORE_A(buf);
        STORE_B(bbuf);
        LOAD_A();                                 // for (t,e1)
        asm volatile("s_waitcnt lgkmcnt(0)\n\ts_barrier" ::: "memory");
        COMPUTE(buf, bbuf);
#pragma unroll
        for (int mi = 0; mi < 4; ++mi)
#pragma unroll
            for (int ni = 0; ni < 4; ++ni)
#pragma unroll
                for (int c = 0; c < 4; ++c)
                    accS[mi][ni][c] += acc[mi][ni][c] * sv0[ni];
        buf ^= 1;

        // ---- phase e=1 ----
        STORE_A(buf);
        LOAD_A();                                 // for (t,e2)
        if (kB < kEnd) { LOAD_B(kB); kB += 32; }  // next k-step's B
        asm volatile("s_waitcnt lgkmcnt(0)\n\ts_barrier" ::: "memory");
        COMPUTE(buf, bbuf);
#pragma unroll
        for (int mi = 0; mi < 4; ++mi)
#pragma unroll
            for (int ni = 0; ni < 4; ++ni)
#pragma unroll
                for (int c = 0; c < 4; ++c)
                    accS[mi][ni][c] += acc[mi][ni][c] * sv1[ni];
        buf ^= 1;

        // ---- phase e=2 ----
        STORE_A(buf);
        if (t + 1 < nkz) LOAD_A();                // for (t+1,e0)
        asm volatile("s_waitcnt lgkmcnt(0)\n\ts_barrier" ::: "memory");
        COMPUTE(buf, bbuf);
#pragma unroll
        for (int mi = 0; mi < 4; ++mi)
#pragma unroll
            for (int ni = 0; ni < 4; ++ni) {
#pragma unroll
                for (int c = 0; c < 4; ++c)
                    accS[mi][ni][c] += acc[mi][ni][c] * sv2[ni];
                acc[mi][ni] = (f32x4){0.f, 0.f, 0.f, 0.f};  // step reset
            }
        buf ^= 1;
        bbuf ^= 1;
    }

    // ---- epilogue: plain store (z==1) or atomicAdd (split-K) ----
    const bool atom = (gridDim.z > 1);
#pragma unroll
    for (int ni = 0; ni < 4; ++ni) {
        int n = n0 + wn + ni * 16 + lm;
#pragma unroll
        for (int mi = 0; mi < 4; ++mi)
#pragma unroll
            for (int r = 0; r < 4; ++r) {
                int m = m0 + wm + mi * 16 + qd * 4 + r;
                if (m >= M) continue;
                float v = accS[mi][ni][r];
                if (atom) atomicAdd(&Cout[(size_t)n * M + m], v);
                else      Cout[(size_t)n * M + m] = v;
            }
    }
}

// ---------------------------------------------------------------------------
// Layer-1 conv GEMM (Ci=3, stride 2): gather path, transposed output.
// ---------------------------------------------------------------------------
__global__ __launch_bounds__(256, 2)
void cgemm_l1_kernel(const u16* __restrict__ Whi, const u16* __restrict__ Wlo,
                     const u32* __restrict__ Bpk, const float* __restrict__ rptr,
                     float* __restrict__ Cout, int M, int N)
{
    __shared__ __align__(16) u16 Ah[2][128 * 40], Al[2][128 * 40];
    __shared__ __align__(16) u16 Bh[2][128 * 40], Bl[2][128 * 40];
    const int tid = threadIdx.x;
    const int bx = xcd_swz(blockIdx.x, gridDim.x);
    const int n0 = bx << 7;
    const int Kper = 27, Kpad = 32;
    const int H = 32, W = 32;

    const int rowA = tid >> 1, kh16 = (tid & 1) << 4;
    const int nB = tid & 127, kOff = (tid >> 7) << 4;

    const int nn = n0 + nB;
    const int bB = nn >> 8;
    const int sidx = nn & 255;
    const int ohs = (sidx >> 4) * 2 - 1;
    const int ows = (sidx & 15) * 2 - 1;
    const long nBase = (long)bB * 3072 + (long)ohs * W + ows;

    const int lane = tid & 63, wv = tid >> 6;
    const int lm = lane & 15, qd = lane >> 4;
    const int wm = (wv & 1) << 6, wn = (wv >> 1) << 6;

    float rsv[3][4];
#pragma unroll
    for (int ni = 0; ni < 4; ++ni) {
        int n = n0 + wn + ni * 16 + lm;
        int b = n >> 8;
#pragma unroll
        for (int e = 0; e < 3; ++e) rsv[e][ni] = rptr[b * 3 + e];
    }

    f32x4 acc[4][4], accS[4][4];
#pragma unroll
    for (int i = 0; i < 4; ++i)
#pragma unroll
        for (int j = 0; j < 4; ++j) {
            acc[i][j]  = (f32x4){0.f, 0.f, 0.f, 0.f};
            accS[i][j] = (f32x4){0.f, 0.f, 0.f, 0.f};
        }

    const int mg = rowA;
    int eL = 0;
    uint4 pA0, pA1, pA2, pA3;
    u32 pB[16];

    auto LOAD = [&]() {
        size_t aOff = ((size_t)(eL * M + mg)) * Kpad + kh16;
        const u16* hp = Whi + aOff;
        const u16* lp = Wlo + aOff;
        pA0 = *(const uint4*)hp; pA1 = *(const uint4*)(hp + 8);
        pA2 = *(const uint4*)lp; pA3 = *(const uint4*)(lp + 8);
#pragma unroll
        for (int j = 0; j < 16; ++j) {
            int k = kOff + j;
            int ci = (int)((unsigned)k / 9u);
            int r9 = k - ci * 9;
            int kh = (int)(((unsigned)r9 * 11u) >> 5);
            int kw = r9 - kh * 3;
            int ih = ohs + kh, iw = ows + kw;
            u32 p = 0;
            if (k < Kper && (unsigned)ih < (unsigned)H && (unsigned)iw < (unsigned)W)
                p = Bpk[nBase + (long)ci * 1024 + kh * W + kw];
            pB[j] = p;
        }
    };
    auto STORE = [&](int buf) {
        *(uint4*)(&Ah[buf][rowA * 40 + kh16])     = pA0;
        *(uint4*)(&Ah[buf][rowA * 40 + kh16 + 8]) = pA1;
        *(uint4*)(&Al[buf][rowA * 40 + kh16])     = pA2;
        *(uint4*)(&Al[buf][rowA * 40 + kh16 + 8]) = pA3;
        u32 hw[8], lw[8];
#pragma unroll
        for (int j = 0; j < 8; ++j) {
            u32 p0 = pB[2 * j], p1 = pB[2 * j + 1];
            hw[j] = (p0 >> 16) | (p1 & 0xffff0000u);
            lw[j] = (p0 & 0xffffu) | (p1 << 16);
        }
        *(uint4*)(&Bh[buf][nB * 40 + kOff])     = make_uint4(hw[0], hw[1], hw[2], hw[3]);
        *(uint4*)(&Bh[buf][nB * 40 + kOff + 8]) = make_uint4(hw[4], hw[5], hw[6], hw[7]);
        *(uint4*)(&Bl[buf][nB * 40 + kOff])     = make_uint4(lw[0], lw[1], lw[2], lw[3]);
        *(uint4*)(&Bl[buf][nB * 40 + kOff + 8]) = make_uint4(lw[4], lw[5], lw[6], lw[7]);
    };
    auto COMPUTE = [&](int buf) {
        bf16x8 ah[4], al[4];
#pragma unroll
        for (int mi = 0; mi < 4; ++mi) {
            int row = wm + mi * 16 + lm;
            ah[mi] = *(const bf16x8*)(&Ah[buf][row * 40 + qd * 8]);
            al[mi] = *(const bf16x8*)(&Al[buf][row * 40 + qd * 8]);
        }
        __builtin_amdgcn_s_setprio(1);
#pragma unroll
        for (int ni = 0; ni < 4; ++ni) {
            int row = wn + ni * 16 + lm;
            bf16x8 bh = *(const bf16x8*)(&Bh[buf][row * 40 + qd * 8]);
            bf16x8 bl = *(const bf16x8*)(&Bl[buf][row * 40 + qd * 8]);
#pragma unroll
            for (int mi = 0; mi < 4; ++mi) {
                f32x4 c = acc[mi][ni];
                c = __builtin_amdgcn_mfma_f32_16x16x32_bf16(al[mi], bh, c, 0, 0, 0);
                c = __builtin_amdgcn_mfma_f32_16x16x32_bf16(ah[mi], bl, c, 0, 0, 0);
                c = __builtin_amdgcn_mfma_f32_16x16x32_bf16(ah[mi], bh, c, 0, 0, 0);
                acc[mi][ni] = c;
            }
        }
        __builtin_amdgcn_s_setprio(0);
    };

    LOAD(); ++eL;
    int buf = 0;
#pragma unroll
    for (int e = 0; e < 3; ++e) {
        STORE(buf);
        if (e < 2) { LOAD(); ++eL; }
        asm volatile("s_waitcnt lgkmcnt(0)\n\ts_barrier" ::: "memory");
        COMPUTE(buf);
        buf ^= 1;
#pragma unroll
        for (int mi = 0; mi < 4; ++mi)
#pragma unroll
            for (int ni = 0; ni < 4; ++ni) {
                accS[mi][ni] += acc[mi][ni] * rsv[e][ni];
                acc[mi][ni] = (f32x4){0.f, 0.f, 0.f, 0.f};
            }
    }

#pragma unroll
    for (int ni = 0; ni < 4; ++ni) {
        int n = n0 + wn + ni * 16 + lm;
#pragma unroll
        for (int mi = 0; mi < 4; ++mi)
#pragma unroll
            for (int r = 0; r < 4; ++r) {
                int m = wm + mi * 16 + qd * 4 + r;
                if (m >= M) continue;
                Cout[(size_t)n * M + m] = accS[mi][ni][r];
            }
    }
}

// ---------------------------------------------------------------------------
// FC GEMM: 128Mx128N tile, BK=32, split-K atomics. R14: raw-barrier
// double-buffered pipeline (reg prefetch; lgkmcnt(0)-only barrier).
// ---------------------------------------------------------------------------
template<int BIAS, int TROUT>
__global__ __launch_bounds__(256, 2)
void mgemm_kernel(const u16* __restrict__ Whi, const u16* __restrict__ Wlo,
                  const u32* __restrict__ Bpk, const float* __restrict__ bias,
                  float* __restrict__ Cout,
                  int M, int N, int Kpad, int Kchunk)
{
    __shared__ __align__(16) u16 Ah[2][128 * 40], Al[2][128 * 40];
    __shared__ __align__(16) u32 Bp[2][128 * 36];
    const int tid = threadIdx.x;
    const int n0 = blockIdx.x << 7, m0 = blockIdx.y << 7;
    const int bz = blockIdx.z;
    const int kq0 = bz * Kchunk;
    const int kEnd = kq0 + Kchunk;

    const int rowA = tid >> 1, kh16 = (tid & 1) << 4;
    const int nB = tid & 127, kOff = (tid >> 7) << 4;

    const int lane = tid & 63, wv = tid >> 6;
    const int lm = lane & 15, qd = lane >> 4;
    const int wm = (wv & 1) << 6, wn = (wv >> 1) << 6;

    f32x4 acc[4][4];
#pragma unroll
    for (int i = 0; i < 4; ++i)
#pragma unroll
        for (int j = 0; j < 4; ++j)
            acc[i][j] = (f32x4){0.f, 0.f, 0.f, 0.f};

    const int mg = m0 + rowA;
    uint4 pA0, pA1, pA2, pA3;
    uint4 pQ0, pQ1, pQ2, pQ3;

    auto LOAD = [&](int kq) {
        if (mg < M) {
            const u16* hp = Whi + (size_t)mg * Kpad + kq + kh16;
            const u16* lp = Wlo + (size_t)mg * Kpad + kq + kh16;
            pA0 = *(const uint4*)hp; pA1 = *(const uint4*)(hp + 8);
            pA2 = *(const uint4*)lp; pA3 = *(const uint4*)(lp + 8);
        } else {
            pA0 = make_uint4(0,0,0,0); pA1 = make_uint4(0,0,0,0);
            pA2 = make_uint4(0,0,0,0); pA3 = make_uint4(0,0,0,0);
        }
        const u32* bp = Bpk + (size_t)(n0 + nB) * Kpad + kq + kOff;
        pQ0 = *(const uint4*)bp;
        pQ1 = *(const uint4*)(bp + 4);
        pQ2 = *(const uint4*)(bp + 8);
        pQ3 = *(const uint4*)(bp + 12);
    };
    auto STORE = [&](int buf) {
        *(uint4*)(&Ah[buf][rowA * 40 + kh16])     = pA0;
        *(uint4*)(&Ah[buf][rowA * 40 + kh16 + 8]) = pA1;
        *(uint4*)(&Al[buf][rowA * 40 + kh16])     = pA2;
        *(uint4*)(&Al[buf][rowA * 40 + kh16 + 8]) = pA3;
        u32* bp = &Bp[buf][nB * 36 + kOff];
        *(uint4*)(bp)      = pQ0;
        *(uint4*)(bp + 4)  = pQ1;
        *(uint4*)(bp + 8)  = pQ2;
        *(uint4*)(bp + 12) = pQ3;
    };
    auto COMPUTE = [&](int buf) {
        bf16x8 ah[4], al[4];
#pragma unroll
        for (int mi = 0; mi < 4; ++mi) {
            int row = wm + mi * 16 + lm;
            ah[mi] = *(const bf16x8*)(&Ah[buf][row * 40 + qd * 8]);
            al[mi] = *(const bf16x8*)(&Al[buf][row * 40 + qd * 8]);
        }
        __builtin_amdgcn_s_setprio(1);
#pragma unroll
        for (int ni = 0; ni < 4; ++ni) {
            const u32* bp = &Bp[buf][(wn + ni * 16 + lm) * 36 + qd * 8];
            uint4 p0 = *(const uint4*)bp;
            uint4 p1 = *(const uint4*)(bp + 4);
            union { u32 w[4]; bf16x8 v; } bh, bl;
            bh.w[0] = (p0.x >> 16) | (p0.y & 0xffff0000u);
            bl.w[0] = (p0.x & 0xffffu) | (p0.y << 16);
            bh.w[1] = (p0.z >> 16) | (p0.w & 0xffff0000u);
            bl.w[1] = (p0.z & 0xffffu) | (p0.w << 16);
            bh.w[2] = (p1.x >> 16) | (p1.y & 0xffff0000u);
            bl.w[2] = (p1.x & 0xffffu) | (p1.y << 16);
            bh.w[3] = (p1.z >> 16) | (p1.w & 0xffff0000u);
            bl.w[3] = (p1.z & 0xffffu) | (p1.w << 16);
#pragma unroll
            for (int mi = 0; mi < 4; ++mi) {
                f32x4 c = acc[mi][ni];
                c = __builtin_amdgcn_mfma_f32_16x16x32_bf16(al[mi], bh.v, c, 0, 0, 0);
                c = __builtin_amdgcn_mfma_f32_16x16x32_bf16(ah[mi], bl.v, c, 0, 0, 0);
                c = __builtin_amdgcn_mfma_f32_16x16x32_bf16(ah[mi], bh.v, c, 0, 0, 0);
                acc[mi][ni] = c;
            }
        }
        __builtin_amdgcn_s_setprio(0);
    };

    LOAD(kq0);
    int buf = 0;
    for (int kq = kq0; kq < kEnd; kq += 32) {
        STORE(buf);
        if (kq + 32 < kEnd) LOAD(kq + 32);   // in flight across the barrier
        asm volatile("s_waitcnt lgkmcnt(0)\n\ts_barrier" ::: "memory");
        COMPUTE(buf);
        buf ^= 1;
    }

#pragma unroll
    for (int ni = 0; ni < 4; ++ni) {
        int n = n0 + wn + ni * 16 + lm;
        if (n >= N) continue;
#pragma unroll
        for (int mi = 0; mi < 4; ++mi)
#pragma unroll
            for (int r = 0; r < 4; ++r) {
                int m = m0 + wm + mi * 16 + qd * 4 + r;
                if (m >= M) continue;
                float v = acc[mi][ni][r];
                if (BIAS && bz == 0) v += bias[m];
                if (TROUT) atomicAdd(&Cout[(size_t)n * M + m], v);
                else       atomicAdd(&Cout[(size_t)m * N + n], v);
            }
    }
}

// elementwise fp32 -> packed bf16x2
__global__ __launch_bounds__(256)
void pack_kernel(const float* __restrict__ in, u32* __restrict__ outp, int count)
{
    int i = blockIdx.x * 256 + threadIdx.x;
    if (i >= count) return;
    outp[i] = packsplit(in[i]);
}

// 2x2/2 maxpool + relu: [B][Hin][Win][C] fp32 -> halo'd packed [B][OH+2][OW+2][C]
__global__ __launch_bounds__(256)
void pool_pack_cl_kernel(const float* __restrict__ in, u32* __restrict__ outp,
                         int Bn, int Hin, int Win, int C)
{
    int OH = Hin >> 1, OW = Win >> 1, H2 = OH + 2, W2 = OW + 2;
    int total = Bn * H2 * W2 * C;
    int i = blockIdx.x * 256 + threadIdx.x;
    if (i >= total) return;
    int c = i % C; int t = i / C;
    int w = t % W2; t /= W2;
    int h = t % H2; int b = t / H2;
    u32 pv = 0;
    if (h >= 1 && h <= OH && w >= 1 && w <= OW) {
        int oh = h - 1, ow = w - 1;
        const float* p = in + (((size_t)b * Hin + 2 * oh) * Win + 2 * ow) * C + c;
        size_t rs = (size_t)Win * C;
        float v = fmaxf(fmaxf(p[0], p[C]), fmaxf(p[rs], p[rs + C]));
        pv = packsplit(fmaxf(v, 0.f));
    }
    outp[i] = pv;
}

// relu (no pool): [B][Hin][Win][C] fp32 -> halo'd packed [B][Hin+2][Win+2][C]
__global__ __launch_bounds__(256)
void pack_cl_kernel(const float* __restrict__ in, u32* __restrict__ outp,
                    int Bn, int Hin, int Win, int C)
{
    int H2 = Hin + 2, W2 = Win + 2;
    int total = Bn * H2 * W2 * C;
    int i = blockIdx.x * 256 + threadIdx.x;
    if (i >= total) return;
    int c = i % C; int t = i / C;
    int w = t % W2; t /= W2;
    int h = t % H2; int b = t / H2;
    u32 pv = 0;
    if (h >= 1 && h <= Hin && w >= 1 && w <= Win) {
        float v = in[(((size_t)b * Hin + (h - 1)) * Win + (w - 1)) * C + c];
        pv = packsplit(fmaxf(v, 0.f));
    }
    outp[i] = pv;
}

// L5 out [B][4][4][256] fp32 --relu+pool--> packed hT[b][f]
__global__ __launch_bounds__(256)
void pool_flatten_cl_kernel(const float* __restrict__ in, u32* __restrict__ outp)
{
    int i = blockIdx.x * 256 + threadIdx.x;
    if (i >= 512 * 1024) return;
    int b = i >> 10;
    int f = i & 1023;
    int c = f >> 2, sp = f & 3;
    int oh = sp >> 1, ow = sp & 1;
    const float* p = in + (((size_t)b * 4 + 2 * oh) * 4 + 2 * ow) * 256 + c;
    float v = fmaxf(fmaxf(p[0], p[256]), fmaxf(p[1024], p[1024 + 256]));
    outp[i] = packsplit(fmaxf(v, 0.f));
}

// FC act: fp32 [Mt][Nt] --relu--> packed transposed [Nt][Mt]
__global__ __launch_bounds__(256)
void tp_pack_kernel(const float* __restrict__ in, u32* __restrict__ outp,
                    int Mt, int Nt)
{
    __shared__ float t[32][33];
    int tx = threadIdx.x & 31, ty = threadIdx.x >> 5;
    int mB = blockIdx.x << 5, nB = blockIdx.y << 5;
#pragma unroll
    for (int i = 0; i < 4; ++i) {
        int mm = ty + i * 8;
        t[mm][tx] = in[(size_t)(mB + mm) * Nt + nB + tx];
    }
    __syncthreads();
#pragma unroll
    for (int i = 0; i < 4; ++i) {
        int nn = ty + i * 8;
        float v = fmaxf(t[tx][nn], 0.f);
        outp[(size_t)(nB + nn) * Mt + mB + tx] = packsplit(v);
    }
}

extern "C" void kernel_launch(void* const* d_in, const int* in_sizes, int n_in,
                              void* d_out, int out_size, void* d_ws, size_t ws_size,
                              hipStream_t stream)
{
    const float* x    = (const float*)d_in[0];
    const float* dw1  = (const float*)d_in[1];
    const float* rw1  = (const float*)d_in[2];
    const float* rb1  = (const float*)d_in[3];
    const float* dw2  = (const float*)d_in[4];
    const float* rw2  = (const float*)d_in[5];
    const float* rb2  = (const float*)d_in[6];
    const float* dw3  = (const float*)d_in[7];
    const float* rw3  = (const float*)d_in[8];
    const float* rb3  = (const float*)d_in[9];
    const float* cw4  = (const float*)d_in[10];
    const float* cr4w = (const float*)d_in[11];
    const float* cr4b = (const float*)d_in[12];
    const float* cw5  = (const float*)d_in[13];
    const float* cr5w = (const float*)d_in[14];
    const float* cr5b = (const float*)d_in[15];
    const float* fw1  = (const float*)d_in[16];
    const float* fb1  = (const float*)d_in[17];
    const float* fw2  = (const float*)d_in[18];
    const float* fb2  = (const float*)d_in[19];
    const float* fw3  = (const float*)d_in[20];
    const float* fb3  = (const float*)d_in[21];
    float* out = (float*)d_out;

    // ---- workspace (float units); layout as R10 ----
    float* ws    = (float*)d_ws;
    float* r1    = ws;
    float* r2    = r1 + 1536;
    float* r3    = r2 + 1536;
    float* r4    = r3 + 1536;
    float* r5    = r4 + 1536;
    float* sdesc = ws + 8192 + 65536;
    const size_t REGION = 18874368;           // 75.5 MB region
    float* region = sdesc + 196608;
    float* slab   = region;                   // fp32 out-slab (front)
    u32*   a3u    = (u32*)(region + 4194304); // [512][6][6][384] packed u32
    u16*   regEnd = (u16*)(region + REGION);
    u32*   P1     = (u32*)(region + REGION);  // 6,291,456 u32 (25.2 MB)

    u16 *w1h = regEnd - 2*(size_t)6144,     *w1l = regEnd - (size_t)6144;
    u16 *w2h = regEnd - 2*(size_t)331776,   *w2l = regEnd - (size_t)331776;
    u16 *w3h = regEnd - 2*(size_t)1990656,  *w3l = regEnd - (size_t)1990656;
    u16 *w4h = regEnd - 2*(size_t)2654208,  *w4l = regEnd - (size_t)2654208;
    u16 *w5h = regEnd - 2*(size_t)1769472,  *w5l = regEnd - (size_t)1769472;
    u16 *f1h = regEnd - 2*(size_t)4194304,  *f1l = regEnd - (size_t)4194304;
    u16 *f2h = regEnd - 2*(size_t)16777216, *f2l = regEnd - (size_t)16777216;
    u16 *f3h = regEnd - 2*(size_t)409600,   *f3l = regEnd - (size_t)409600;

    u32* xpk   = P1;                 // [B][3][32][32]
    u32* a1    = P1;                 // [512][10][10][64]
    u32* a2    = P1;                 // [512][6][6][192]
    u32* a4    = P1;                 // [512][6][6][256]
    u32* hTpk  = P1;                 // [512][1024]
    u32* f1pkT = P1 + 1048576;
    u32* f2pkT = P1 + 3145728;

    const int B = 512;

    // ---- input pack ----
    pack_kernel<<<6144, 256, 0, stream>>>(x, xpk, 1572864);

    // ---- Layer 1: DyRes conv 3->64, s2 p1 -> slab [B][16][16][64] ----
    wsplit_kernel<<<24, 256, 0, stream>>>(dw1, w1h, w1l, 6144, 27, 32);
    stats_kernel<<<B * 3, 64, 0, stream>>>(x, sdesc, 3, 1024, 1);
    routing_kernel<<<B, 64, 0, stream>>>(sdesc, rw1, rb1, r1, 3, 1);
    cgemm_l1_kernel<<<dim3(1024, 1, 1), 256, 0, stream>>>(
        w1h, w1l, xpk, r1, slab, 64, 131072);
    pool_pack_cl_kernel<<<12800, 256, 0, stream>>>(slab, a1, B, 16, 16, 64);

    // ---- Layer 2: DyRes conv 64->192 -> slab [B][8][8][192] ----
    wsplit_cl_kernel<<<1296, 256, 0, stream>>>(dw2, w2h, w2l, 331776, 64);
    stats_cl_kernel<<<B, 64, 0, stream>>>(a1, sdesc, 10, 10, 64, 1);
    routing_kernel<<<B, 64, 0, stream>>>(sdesc, rw2, rb2, r2, 64, 1);
    cgemm_cl_kernel<64, 10, 10, 6, 3><<<dim3(256, 2, 1), 256, 0, stream>>>(
        w2h, w2l, a1, r2, slab, 192, 32768, 576, 576);
    pool_pack_cl_kernel<<<13824, 256, 0, stream>>>(slab, a2, B, 8, 8, 192);

    // ---- Layer 3: DyRes conv 192->384 -> slab [B][4][4][384] ----
    wsplit_cl_kernel<<<7776, 256, 0, stream>>>(dw3, w3h, w3l, 1990656, 192);
    stats_cl_kernel<<<B, 192, 0, stream>>>(a2, sdesc, 6, 6, 192, 1);
    routing_kernel<<<B, 64, 0, stream>>>(sdesc, rw3, rb3, r3, 192, 1);
    hipMemsetAsync(slab, 0, (size_t)8192 * 384 * 4, stream);
    cgemm_cl_kernel<192, 6, 6, 4, 2><<<dim3(64, 3, 2), 256, 0, stream>>>(
        w3h, w3l, a2, r3, slab, 384, 8192, 1728, 864);
    pack_cl_kernel<<<27648, 256, 0, stream>>>(slab, a3u, B, 4, 4, 384);

    // ---- Layer 4: CondConv 384->256 -> slab [B][4][4][256] ----
    wsplit_cl_kernel<<<10368, 256, 0, stream>>>(cw4, w4h, w4l, 2654208, 384);
    stats_cl_kernel<<<B, 384, 0, stream>>>(a3u, sdesc, 6, 6, 384, 0);
    routing_kernel<<<B, 64, 0, stream>>>(sdesc, cr4w, cr4b, r4, 384, 0);
    hipMemsetAsync(slab, 0, (size_t)8192 * 256 * 4, stream);
    cgemm_cl_kernel<384, 6, 6, 4, 2><<<dim3(64, 2, 4), 256, 0, stream>>>(
        w4h, w4l, a3u, r4, slab, 256, 8192, 3456, 864);
    pack_cl_kernel<<<18432, 256, 0, stream>>>(slab, a4, B, 4, 4, 256);

    // ---- Layer 5: CondConv 256->256 -> slab [B][4][4][256] ----
    wsplit_cl_kernel<<<6912, 256, 0, stream>>>(cw5, w5h, w5l, 1769472, 256);
    stats_cl_kernel<<<B, 256, 0, stream>>>(a4, sdesc, 6, 6, 256, 0);
    routing_kernel<<<B, 64, 0, stream>>>(sdesc, cr5w, cr5b, r5, 256, 0);
    hipMemsetAsync(slab, 0, (size_t)8192 * 256 * 4, stream);
    cgemm_cl_kernel<256, 6, 6, 4, 2><<<dim3(64, 2, 4), 256, 0, stream>>>(
        w5h, w5l, a4, r5, slab, 256, 8192, 2304, 576);

    // ---- relu + pool + flatten -> packed hT [512][1024] ----
    pool_flatten_cl_kernel<<<2048, 256, 0, stream>>>(slab, hTpk);

    // ---- FC1: 1024 -> 4096 ----
    wsplit_kernel<<<16384, 256, 0, stream>>>(fw1, f1h, f1l, 4194304, 1024, 1024);
    hipMemsetAsync(slab, 0, (size_t)4096 * 512 * 4, stream);
    mgemm_kernel<1, 0><<<dim3(4, 32, 8), 256, 0, stream>>>(
        f1h, f1l, hTpk, fb1, slab, 4096, 512, 1024, 128);
    tp_pack_kernel<<<dim3(128, 16), 256, 0, stream>>>(slab, f1pkT, 4096, 512);

    // ---- FC2: 4096 -> 4096 ----
    wsplit_kernel<<<65536, 256, 0, stream>>>(fw2, f2h, f2l, 16777216, 4096, 4096);
    hipMemsetAsync(slab, 0, (size_t)4096 * 512 * 4, stream);
    mgemm_kernel<1, 0><<<dim3(4, 32, 8), 256, 0, stream>>>(
        f2h, f2l, f1pkT, fb2, slab, 4096, 512, 4096, 512);
    tp_pack_kernel<<<dim3(128, 16), 256, 0, stream>>>(slab, f2pkT, 4096, 512);

    // ---- FC3: 4096 -> 100 -> d_out [512, 100] ----
    wsplit_kernel<<<1600, 256, 0, stream>>>(fw3, f3h, f3l, 409600, 4096, 4096);
    hipMemsetAsync(out, 0, (size_t)512 * 100 * 4, stream);
    mgemm_kernel<1, 1><<<dim3(4, 1, 32), 256, 0, stream>>>(
        f3h, f3l, f2pkT, fb3, out, 100, 512, 4096, 128);
}

// Round 9
// 1485.586 us; speedup vs baseline: 1.7747x; 1.6862x over previous
//
#include <hip/hip_runtime.h>
#include <math.h>

// ---------------------------------------------------------------------------
// DyRes/CondConv AlexNet forward. R15 = R10 convs (verbatim; best verified)
// + pipelined FC mgemm (the only R13/R14 piece that is register-safe).
// R13/R14 post-mortem: k-outer/expert-inner needs acc+accS both hot in every
// phase -> unified-file overflow -> scratch spill (1-2 GB R+W). Abandoned.
// R10 expert-outer conv GEMM restored exactly. FC mgemm gets the proven
// raw-barrier double-buffered pipeline (reg prefetch + lgkmcnt(0)-only
// barrier + setprio), same structure that took convs 12%->21% MfmaUtil.
// ---------------------------------------------------------------------------

typedef unsigned short u16;
typedef unsigned int u32;
typedef short bf16x8 __attribute__((ext_vector_type(8)));
typedef float f32x4 __attribute__((ext_vector_type(4)));

__device__ __forceinline__ u16 bf16_rne(float f) {
    u32 u = __float_as_uint(f);
    return (u16)((u + 0x7fffu + ((u >> 16) & 1u)) >> 16);
}
__device__ __forceinline__ u32 packsplit(float v) {
    u16 h = bf16_rne(v);
    float hf = __uint_as_float((u32)h << 16);
    u16 l = bf16_rne(v - hf);
    return ((u32)h << 16) | l;
}
__device__ __forceinline__ float unpackf(u32 p) {
    return __uint_as_float(p & 0xffff0000u) + __uint_as_float(p << 16);
}
__device__ __forceinline__ int xcd_swz(int bid, int n) {
    // bijective when n % 8 == 0 (all conv grids satisfy this)
    if ((n & 7) != 0) return bid;
    int cpx = n >> 3;
    return (bid & 7) * cpx + (bid >> 3);
}

// fp32 weights -> K-padded bf16 hi/lo planes, source k-order (ci,kh,kw)
__global__ __launch_bounds__(256)
void wsplit_kernel(const float* __restrict__ W, u16* __restrict__ whi,
                   u16* __restrict__ wlo, int total, int Kper, int Kpad)
{
    int idx = blockIdx.x * 256 + threadIdx.x;
    if (idx >= total) return;
    int r = idx / Kpad, k = idx - r * Kpad;
    float v = (k < Kper) ? W[(size_t)r * Kper + k] : 0.f;
    u16 h = bf16_rne(v);
    whi[idx] = h;
    wlo[idx] = bf16_rne(v - __uint_as_float((u32)h << 16));
}

// fp32 weights -> bf16 hi/lo planes with k-order permuted to (kh,kw,ci)
__global__ __launch_bounds__(256)
void wsplit_cl_kernel(const float* __restrict__ W, u16* __restrict__ whi,
                      u16* __restrict__ wlo, int total, int Ci)
{
    int idx = blockIdx.x * 256 + threadIdx.x;
    if (idx >= total) return;
    int Kper = 9 * Ci;
    int r = idx / Kper, kp = idx - r * Kper;
    int cell = kp / Ci, ci = kp - cell * Ci;        // kp = cell*Ci + ci
    float v = W[(size_t)r * Kper + ci * 9 + cell];  // src k = ci*9 + kh*3 + kw
    u16 h = bf16_rne(v);
    whi[idx] = h;
    wlo[idx] = bf16_rne(v - __uint_as_float((u32)h << 16));
}

// stats over fp32 [B][C][HW] (layer-1 input only)
__global__ __launch_bounds__(64)
void stats_kernel(const float* __restrict__ actv, float* __restrict__ s,
                  int C, int HW, int use_std)
{
    int idx = blockIdx.x;           // b*C + c
    size_t base = (size_t)idx * HW;
    int lane = threadIdx.x;
    float sum = 0.f, sq = 0.f;
    const float* p = actv + base;
    for (int i = lane; i < HW; i += 64) { float v = p[i]; sum += v; sq += v * v; }
#pragma unroll
    for (int off = 32; off > 0; off >>= 1) {
        sum += __shfl_down(sum, off);
        sq  += __shfl_down(sq, off);
    }
    if (lane == 0) {
        float inv = 1.f / (float)HW;
        float mean = sum * inv;
        float var = sq * inv - mean * mean;
        float outv = mean;
        if (use_std) outv += sqrtf(fmaxf(var, 0.f));
        s[idx] = outv;
    }
}

// stats over packed channels-last halo'd act [B][H2][W2][C]; block=C, grid=B
__global__ __launch_bounds__(384)
void stats_cl_kernel(const u32* __restrict__ act, float* __restrict__ s,
                     int H2, int W2, int C, int use_std)
{
    int b = blockIdx.x, c = threadIdx.x;
    int Hin = H2 - 2, Win = W2 - 2;
    float sum = 0.f, sq = 0.f;
    for (int h = 0; h < Hin; ++h)
        for (int w = 0; w < Win; ++w) {
            float v = unpackf(act[(((size_t)b * H2 + h + 1) * W2 + w + 1) * C + c]);
            sum += v; sq += v * v;
        }
    float inv = 1.f / (float)(Hin * Win);
    float mean = sum * inv;
    float var = sq * inv - mean * mean;
    float outv = mean;
    if (use_std) outv += sqrtf(fmaxf(var, 0.f));
    s[b * C + c] = outv;
}

__global__ __launch_bounds__(64)
void routing_kernel(const float* __restrict__ s, const float* __restrict__ rw,
                    const float* __restrict__ rb, float* __restrict__ r,
                    int C, int softmax_mode)
{
    int b = blockIdx.x;
    int lane = threadIdx.x;
    float d0 = 0.f, d1 = 0.f, d2 = 0.f;
    for (int c = lane; c < C; c += 64) {
        float sv = s[b * C + c];
        d0 += sv * rw[c];
        d1 += sv * rw[C + c];
        d2 += sv * rw[2 * C + c];
    }
#pragma unroll
    for (int off = 32; off > 0; off >>= 1) {
        d0 += __shfl_down(d0, off);
        d1 += __shfl_down(d1, off);
        d2 += __shfl_down(d2, off);
    }
    if (lane == 0) {
        d0 += rb[0]; d1 += rb[1]; d2 += rb[2];
        if (softmax_mode) {
            float mx = fmaxf(d0, fmaxf(d1, d2));
            float e0 = expf(d0 - mx), e1 = expf(d1 - mx), e2 = expf(d2 - mx);
            float inv = 1.f / (e0 + e1 + e2);
            r[b * 3 + 0] = e0 * inv;
            r[b * 3 + 1] = e1 * inv;
            r[b * 3 + 2] = e2 * inv;
        } else {
            r[b * 3 + 0] = 1.f / (1.f + expf(-d0));
            r[b * 3 + 1] = 1.f / (1.f + expf(-d1));
            r[b * 3 + 2] = 1.f / (1.f + expf(-d2));
        }
    }
}

// ---------------------------------------------------------------------------
// Channels-last expert-fused conv GEMM (L2-L5), R10 verbatim. Tile 128Mx128N,
// BK=32, 4 waves. B from halo'd act [B][H2][W2][CI] packed u32, k-order
// (kh,kw,ci): 16-k fragment = 16 contiguous u32 -> 4 dwordx4 loads, split to
// bf16 hi/lo at stage time. Experts outer-looped in-kernel (dual acc).
// Pipeline: STORE(regs) -> issue next loads -> {lgkmcnt(0); s_barrier}
// (no vmcnt drain) -> compute. Output transposed C[n*M + m].
// ---------------------------------------------------------------------------
template<int CI, int H2, int W2, int LGS, int LGOW>
__global__ __launch_bounds__(256, 2)
void cgemm_cl_kernel(const u16* __restrict__ Whi, const u16* __restrict__ Wlo,
                     const u32* __restrict__ Bpk, const float* __restrict__ rptr,
                     float* __restrict__ Cout, int M, int N, int Kper, int Kchunk)
{
    __shared__ __align__(16) u16 Ah[2][128 * 40], Al[2][128 * 40];
    __shared__ __align__(16) u16 Bh[2][128 * 40], Bl[2][128 * 40];
    const int tid = threadIdx.x;
    const int bx = xcd_swz(blockIdx.x, gridDim.x);
    const int n0 = bx << 7, m0 = blockIdx.y << 7;
    const int kq0 = blockIdx.z * Kchunk;

    const int rowA = tid >> 1, kh16 = (tid & 1) << 4;
    const int nB = tid & 127, kOff = (tid >> 7) << 4;

    const int nn = n0 + nB;
    const int bB = nn >> LGS;
    const int sidx = nn & ((1 << LGS) - 1);
    const int oh = sidx >> LGOW, ow = sidx & ((1 << LGOW) - 1);
    const long nBase = ((long)(bB * H2 + oh) * W2 + ow) * CI;

    const int lane = tid & 63, wv = tid >> 6;
    const int lm = lane & 15, qd = lane >> 4;
    const int wm = (wv & 1) << 6, wn = (wv >> 1) << 6;

    float rsv[3][4];
#pragma unroll
    for (int ni = 0; ni < 4; ++ni) {
        int n = n0 + wn + ni * 16 + lm;
        int b = n >> LGS;
#pragma unroll
        for (int e = 0; e < 3; ++e) rsv[e][ni] = rptr[b * 3 + e];
    }

    f32x4 acc[4][4], accS[4][4];
#pragma unroll
    for (int i = 0; i < 4; ++i)
#pragma unroll
        for (int j = 0; j < 4; ++j) {
            acc[i][j]  = (f32x4){0.f, 0.f, 0.f, 0.f};
            accS[i][j] = (f32x4){0.f, 0.f, 0.f, 0.f};
        }

    const int mg = m0 + rowA;
    const int nkz = Kchunk >> 5;
    const int NS = 3 * nkz;

    int eL = 0, kL = kq0;
    uint4 pA0, pA1, pA2, pA3;
    uint4 pQ0, pQ1, pQ2, pQ3;

    auto LOAD = [&]() {
        size_t aOff = ((size_t)(eL * M + mg)) * Kper + kL + kh16;
        const u16* hp = Whi + aOff;
        const u16* lp = Wlo + aOff;
        pA0 = *(const uint4*)hp; pA1 = *(const uint4*)(hp + 8);
        pA2 = *(const uint4*)lp; pA3 = *(const uint4*)(lp + 8);
        int k = kL + kOff;
        int cell = k / CI;               // CI constant -> folded
        int ci0 = k - cell * CI;
        int kh = (cell * 11) >> 5;
        int kw = cell - kh * 3;
        const u32* bp = Bpk + (nBase + (long)((kh * W2 + kw) * CI + ci0));
        pQ0 = *(const uint4*)bp;
        pQ1 = *(const uint4*)(bp + 4);
        pQ2 = *(const uint4*)(bp + 8);
        pQ3 = *(const uint4*)(bp + 12);
    };
    auto ADV = [&]() {
        kL += 32;
        if (kL == kq0 + Kchunk) { kL = kq0; ++eL; }
    };
    auto STORE = [&](int buf) {
        *(uint4*)(&Ah[buf][rowA * 40 + kh16])     = pA0;
        *(uint4*)(&Ah[buf][rowA * 40 + kh16 + 8]) = pA1;
        *(uint4*)(&Al[buf][rowA * 40 + kh16])     = pA2;
        *(uint4*)(&Al[buf][rowA * 40 + kh16 + 8]) = pA3;
        u32 qv[16] = {pQ0.x, pQ0.y, pQ0.z, pQ0.w, pQ1.x, pQ1.y, pQ1.z, pQ1.w,
                      pQ2.x, pQ2.y, pQ2.z, pQ2.w, pQ3.x, pQ3.y, pQ3.z, pQ3.w};
        u32 hw[8], lw[8];
#pragma unroll
        for (int j = 0; j < 8; ++j) {
            u32 p0 = qv[2 * j], p1 = qv[2 * j + 1];
            hw[j] = (p0 >> 16) | (p1 & 0xffff0000u);
            lw[j] = (p0 & 0xffffu) | (p1 << 16);
        }
        *(uint4*)(&Bh[buf][nB * 40 + kOff])     = make_uint4(hw[0], hw[1], hw[2], hw[3]);
        *(uint4*)(&Bh[buf][nB * 40 + kOff + 8]) = make_uint4(hw[4], hw[5], hw[6], hw[7]);
        *(uint4*)(&Bl[buf][nB * 40 + kOff])     = make_uint4(lw[0], lw[1], lw[2], lw[3]);
        *(uint4*)(&Bl[buf][nB * 40 + kOff + 8]) = make_uint4(lw[4], lw[5], lw[6], lw[7]);
    };
    auto COMPUTE = [&](int buf) {
        bf16x8 ah[4], al[4];
#pragma unroll
        for (int mi = 0; mi < 4; ++mi) {
            int row = wm + mi * 16 + lm;
            ah[mi] = *(const bf16x8*)(&Ah[buf][row * 40 + qd * 8]);
            al[mi] = *(const bf16x8*)(&Al[buf][row * 40 + qd * 8]);
        }
        __builtin_amdgcn_s_setprio(1);
#pragma unroll
        for (int ni = 0; ni < 4; ++ni) {
            int row = wn + ni * 16 + lm;
            bf16x8 bh = *(const bf16x8*)(&Bh[buf][row * 40 + qd * 8]);
            bf16x8 bl = *(const bf16x8*)(&Bl[buf][row * 40 + qd * 8]);
#pragma unroll
            for (int mi = 0; mi < 4; ++mi) {
                f32x4 c = acc[mi][ni];
                c = __builtin_amdgcn_mfma_f32_16x16x32_bf16(al[mi], bh, c, 0, 0, 0);
                c = __builtin_amdgcn_mfma_f32_16x16x32_bf16(ah[mi], bl, c, 0, 0, 0);
                c = __builtin_amdgcn_mfma_f32_16x16x32_bf16(ah[mi], bh, c, 0, 0, 0);
                acc[mi][ni] = c;
            }
        }
        __builtin_amdgcn_s_setprio(0);
    };

    LOAD(); ADV();
    int s = 0, buf = 0;
#pragma unroll
    for (int e = 0; e < 3; ++e) {
        for (int t = 0; t < nkz; ++t) {
            STORE(buf);
            if (s + 1 < NS) { LOAD(); ADV(); }
            asm volatile("s_waitcnt lgkmcnt(0)\n\ts_barrier" ::: "memory");
            COMPUTE(buf);
            buf ^= 1; ++s;
        }
#pragma unroll
        for (int mi = 0; mi < 4; ++mi)
#pragma unroll
            for (int ni = 0; ni < 4; ++ni) {
                accS[mi][ni] += acc[mi][ni] * rsv[e][ni];
                acc[mi][ni] = (f32x4){0.f, 0.f, 0.f, 0.f};
            }
    }

    const bool atom = (gridDim.z > 1);
#pragma unroll
    for (int ni = 0; ni < 4; ++ni) {
        int n = n0 + wn + ni * 16 + lm;
#pragma unroll
        for (int mi = 0; mi < 4; ++mi)
#pragma unroll
            for (int r = 0; r < 4; ++r) {
                int m = m0 + wm + mi * 16 + qd * 4 + r;
                if (m >= M) continue;
                float v = accS[mi][ni][r];
                if (atom) atomicAdd(&Cout[(size_t)n * M + m], v);
                else      Cout[(size_t)n * M + m] = v;
            }
    }
}

// ---------------------------------------------------------------------------
// Layer-1 conv GEMM (Ci=3, stride 2): gather path, transposed output.
// ---------------------------------------------------------------------------
__global__ __launch_bounds__(256, 2)
void cgemm_l1_kernel(const u16* __restrict__ Whi, const u16* __restrict__ Wlo,
                     const u32* __restrict__ Bpk, const float* __restrict__ rptr,
                     float* __restrict__ Cout, int M, int N)
{
    __shared__ __align__(16) u16 Ah[2][128 * 40], Al[2][128 * 40];
    __shared__ __align__(16) u16 Bh[2][128 * 40], Bl[2][128 * 40];
    const int tid = threadIdx.x;
    const int bx = xcd_swz(blockIdx.x, gridDim.x);
    const int n0 = bx << 7;
    const int Kper = 27, Kpad = 32;
    const int H = 32, W = 32;

    const int rowA = tid >> 1, kh16 = (tid & 1) << 4;
    const int nB = tid & 127, kOff = (tid >> 7) << 4;

    const int nn = n0 + nB;
    const int bB = nn >> 8;
    const int sidx = nn & 255;
    const int ohs = (sidx >> 4) * 2 - 1;
    const int ows = (sidx & 15) * 2 - 1;
    const long nBase = (long)bB * 3072 + (long)ohs * W + ows;

    const int lane = tid & 63, wv = tid >> 6;
    const int lm = lane & 15, qd = lane >> 4;
    const int wm = (wv & 1) << 6, wn = (wv >> 1) << 6;

    float rsv[3][4];
#pragma unroll
    for (int ni = 0; ni < 4; ++ni) {
        int n = n0 + wn + ni * 16 + lm;
        int b = n >> 8;
#pragma unroll
        for (int e = 0; e < 3; ++e) rsv[e][ni] = rptr[b * 3 + e];
    }

    f32x4 acc[4][4], accS[4][4];
#pragma unroll
    for (int i = 0; i < 4; ++i)
#pragma unroll
        for (int j = 0; j < 4; ++j) {
            acc[i][j]  = (f32x4){0.f, 0.f, 0.f, 0.f};
            accS[i][j] = (f32x4){0.f, 0.f, 0.f, 0.f};
        }

    const int mg = rowA;
    int eL = 0;
    uint4 pA0, pA1, pA2, pA3;
    u32 pB[16];

    auto LOAD = [&]() {
        size_t aOff = ((size_t)(eL * M + mg)) * Kpad + kh16;
        const u16* hp = Whi + aOff;
        const u16* lp = Wlo + aOff;
        pA0 = *(const uint4*)hp; pA1 = *(const uint4*)(hp + 8);
        pA2 = *(const uint4*)lp; pA3 = *(const uint4*)(lp + 8);
#pragma unroll
        for (int j = 0; j < 16; ++j) {
            int k = kOff + j;
            int ci = (int)((unsigned)k / 9u);
            int r9 = k - ci * 9;
            int kh = (int)(((unsigned)r9 * 11u) >> 5);
            int kw = r9 - kh * 3;
            int ih = ohs + kh, iw = ows + kw;
            u32 p = 0;
            if (k < Kper && (unsigned)ih < (unsigned)H && (unsigned)iw < (unsigned)W)
                p = Bpk[nBase + (long)ci * 1024 + kh * W + kw];
            pB[j] = p;
        }
    };
    auto STORE = [&](int buf) {
        *(uint4*)(&Ah[buf][rowA * 40 + kh16])     = pA0;
        *(uint4*)(&Ah[buf][rowA * 40 + kh16 + 8]) = pA1;
        *(uint4*)(&Al[buf][rowA * 40 + kh16])     = pA2;
        *(uint4*)(&Al[buf][rowA * 40 + kh16 + 8]) = pA3;
        u32 hw[8], lw[8];
#pragma unroll
        for (int j = 0; j < 8; ++j) {
            u32 p0 = pB[2 * j], p1 = pB[2 * j + 1];
            hw[j] = (p0 >> 16) | (p1 & 0xffff0000u);
            lw[j] = (p0 & 0xffffu) | (p1 << 16);
        }
        *(uint4*)(&Bh[buf][nB * 40 + kOff])     = make_uint4(hw[0], hw[1], hw[2], hw[3]);
        *(uint4*)(&Bh[buf][nB * 40 + kOff + 8]) = make_uint4(hw[4], hw[5], hw[6], hw[7]);
        *(uint4*)(&Bl[buf][nB * 40 + kOff])     = make_uint4(lw[0], lw[1], lw[2], lw[3]);
        *(uint4*)(&Bl[buf][nB * 40 + kOff + 8]) = make_uint4(lw[4], lw[5], lw[6], lw[7]);
    };
    auto COMPUTE = [&](int buf) {
        bf16x8 ah[4], al[4];
#pragma unroll
        for (int mi = 0; mi < 4; ++mi) {
            int row = wm + mi * 16 + lm;
            ah[mi] = *(const bf16x8*)(&Ah[buf][row * 40 + qd * 8]);
            al[mi] = *(const bf16x8*)(&Al[buf][row * 40 + qd * 8]);
        }
        __builtin_amdgcn_s_setprio(1);
#pragma unroll
        for (int ni = 0; ni < 4; ++ni) {
            int row = wn + ni * 16 + lm;
            bf16x8 bh = *(const bf16x8*)(&Bh[buf][row * 40 + qd * 8]);
            bf16x8 bl = *(const bf16x8*)(&Bl[buf][row * 40 + qd * 8]);
#pragma unroll
            for (int mi = 0; mi < 4; ++mi) {
                f32x4 c = acc[mi][ni];
                c = __builtin_amdgcn_mfma_f32_16x16x32_bf16(al[mi], bh, c, 0, 0, 0);
                c = __builtin_amdgcn_mfma_f32_16x16x32_bf16(ah[mi], bl, c, 0, 0, 0);
                c = __builtin_amdgcn_mfma_f32_16x16x32_bf16(ah[mi], bh, c, 0, 0, 0);
                acc[mi][ni] = c;
            }
        }
        __builtin_amdgcn_s_setprio(0);
    };

    LOAD(); ++eL;
    int buf = 0;
#pragma unroll
    for (int e = 0; e < 3; ++e) {
        STORE(buf);
        if (e < 2) { LOAD(); ++eL; }
        asm volatile("s_waitcnt lgkmcnt(0)\n\ts_barrier" ::: "memory");
        COMPUTE(buf);
        buf ^= 1;
#pragma unroll
        for (int mi = 0; mi < 4; ++mi)
#pragma unroll
            for (int ni = 0; ni < 4; ++ni) {
                accS[mi][ni] += acc[mi][ni] * rsv[e][ni];
                acc[mi][ni] = (f32x4){0.f, 0.f, 0.f, 0.f};
            }
    }

#pragma unroll
    for (int ni = 0; ni < 4; ++ni) {
        int n = n0 + wn + ni * 16 + lm;
#pragma unroll
        for (int mi = 0; mi < 4; ++mi)
#pragma unroll
            for (int r = 0; r < 4; ++r) {
                int m = wm + mi * 16 + qd * 4 + r;
                if (m >= M) continue;
                Cout[(size_t)n * M + m] = accS[mi][ni][r];
            }
    }
}

// ---------------------------------------------------------------------------
// FC GEMM: 128Mx128N tile, BK=32, split-K atomics. Pipelined (dbuf LDS,
// reg prefetch across lgkmcnt(0)-only raw barrier, setprio).
// ---------------------------------------------------------------------------
template<int BIAS, int TROUT>
__global__ __launch_bounds__(256, 2)
void mgemm_kernel(const u16* __restrict__ Whi, const u16* __restrict__ Wlo,
                  const u32* __restrict__ Bpk, const float* __restrict__ bias,
                  float* __restrict__ Cout,
                  int M, int N, int Kpad, int Kchunk)
{
    __shared__ __align__(16) u16 Ah[2][128 * 40], Al[2][128 * 40];
    __shared__ __align__(16) u32 Bp[2][128 * 36];
    const int tid = threadIdx.x;
    const int n0 = blockIdx.x << 7, m0 = blockIdx.y << 7;
    const int bz = blockIdx.z;
    const int kq0 = bz * Kchunk;
    const int kEnd = kq0 + Kchunk;

    const int rowA = tid >> 1, kh16 = (tid & 1) << 4;
    const int nB = tid & 127, kOff = (tid >> 7) << 4;

    const int lane = tid & 63, wv = tid >> 6;
    const int lm = lane & 15, qd = lane >> 4;
    const int wm = (wv & 1) << 6, wn = (wv >> 1) << 6;

    f32x4 acc[4][4];
#pragma unroll
    for (int i = 0; i < 4; ++i)
#pragma unroll
        for (int j = 0; j < 4; ++j)
            acc[i][j] = (f32x4){0.f, 0.f, 0.f, 0.f};

    const int mg = m0 + rowA;
    uint4 pA0, pA1, pA2, pA3;
    uint4 pQ0, pQ1, pQ2, pQ3;

    auto LOAD = [&](int kq) {
        if (mg < M) {
            const u16* hp = Whi + (size_t)mg * Kpad + kq + kh16;
            const u16* lp = Wlo + (size_t)mg * Kpad + kq + kh16;
            pA0 = *(const uint4*)hp; pA1 = *(const uint4*)(hp + 8);
            pA2 = *(const uint4*)lp; pA3 = *(const uint4*)(lp + 8);
        } else {
            pA0 = make_uint4(0,0,0,0); pA1 = make_uint4(0,0,0,0);
            pA2 = make_uint4(0,0,0,0); pA3 = make_uint4(0,0,0,0);
        }
        const u32* bp = Bpk + (size_t)(n0 + nB) * Kpad + kq + kOff;
        pQ0 = *(const uint4*)bp;
        pQ1 = *(const uint4*)(bp + 4);
        pQ2 = *(const uint4*)(bp + 8);
        pQ3 = *(const uint4*)(bp + 12);
    };
    auto STORE = [&](int buf) {
        *(uint4*)(&Ah[buf][rowA * 40 + kh16])     = pA0;
        *(uint4*)(&Ah[buf][rowA * 40 + kh16 + 8]) = pA1;
        *(uint4*)(&Al[buf][rowA * 40 + kh16])     = pA2;
        *(uint4*)(&Al[buf][rowA * 40 + kh16 + 8]) = pA3;
        u32* bp = &Bp[buf][nB * 36 + kOff];
        *(uint4*)(bp)      = pQ0;
        *(uint4*)(bp + 4)  = pQ1;
        *(uint4*)(bp + 8)  = pQ2;
        *(uint4*)(bp + 12) = pQ3;
    };
    auto COMPUTE = [&](int buf) {
        bf16x8 ah[4], al[4];
#pragma unroll
        for (int mi = 0; mi < 4; ++mi) {
            int row = wm + mi * 16 + lm;
            ah[mi] = *(const bf16x8*)(&Ah[buf][row * 40 + qd * 8]);
            al[mi] = *(const bf16x8*)(&Al[buf][row * 40 + qd * 8]);
        }
        __builtin_amdgcn_s_setprio(1);
#pragma unroll
        for (int ni = 0; ni < 4; ++ni) {
            const u32* bp = &Bp[buf][(wn + ni * 16 + lm) * 36 + qd * 8];
            uint4 p0 = *(const uint4*)bp;
            uint4 p1 = *(const uint4*)(bp + 4);
            union { u32 w[4]; bf16x8 v; } bh, bl;
            bh.w[0] = (p0.x >> 16) | (p0.y & 0xffff0000u);
            bl.w[0] = (p0.x & 0xffffu) | (p0.y << 16);
            bh.w[1] = (p0.z >> 16) | (p0.w & 0xffff0000u);
            bl.w[1] = (p0.z & 0xffffu) | (p0.w << 16);
            bh.w[2] = (p1.x >> 16) | (p1.y & 0xffff0000u);
            bl.w[2] = (p1.x & 0xffffu) | (p1.y << 16);
            bh.w[3] = (p1.z >> 16) | (p1.w & 0xffff0000u);
            bl.w[3] = (p1.z & 0xffffu) | (p1.w << 16);
#pragma unroll
            for (int mi = 0; mi < 4; ++mi) {
                f32x4 c = acc[mi][ni];
                c = __builtin_amdgcn_mfma_f32_16x16x32_bf16(al[mi], bh.v, c, 0, 0, 0);
                c = __builtin_amdgcn_mfma_f32_16x16x32_bf16(ah[mi], bl.v, c, 0, 0, 0);
                c = __builtin_amdgcn_mfma_f32_16x16x32_bf16(ah[mi], bh.v, c, 0, 0, 0);
                acc[mi][ni] = c;
            }
        }
        __builtin_amdgcn_s_setprio(0);
    };

    LOAD(kq0);
    int buf = 0;
    for (int kq = kq0; kq < kEnd; kq += 32) {
        STORE(buf);
        if (kq + 32 < kEnd) LOAD(kq + 32);   // in flight across the barrier
        asm volatile("s_waitcnt lgkmcnt(0)\n\ts_barrier" ::: "memory");
        COMPUTE(buf);
        buf ^= 1;
    }

#pragma unroll
    for (int ni = 0; ni < 4; ++ni) {
        int n = n0 + wn + ni * 16 + lm;
        if (n >= N) continue;
#pragma unroll
        for (int mi = 0; mi < 4; ++mi)
#pragma unroll
            for (int r = 0; r < 4; ++r) {
                int m = m0 + wm + mi * 16 + qd * 4 + r;
                if (m >= M) continue;
                float v = acc[mi][ni][r];
                if (BIAS && bz == 0) v += bias[m];
                if (TROUT) atomicAdd(&Cout[(size_t)n * M + m], v);
                else       atomicAdd(&Cout[(size_t)m * N + n], v);
            }
    }
}

// elementwise fp32 -> packed bf16x2
__global__ __launch_bounds__(256)
void pack_kernel(const float* __restrict__ in, u32* __restrict__ outp, int count)
{
    int i = blockIdx.x * 256 + threadIdx.x;
    if (i >= count) return;
    outp[i] = packsplit(in[i]);
}

// 2x2/2 maxpool + relu: [B][Hin][Win][C] fp32 -> halo'd packed [B][OH+2][OW+2][C]
__global__ __launch_bounds__(256)
void pool_pack_cl_kernel(const float* __restrict__ in, u32* __restrict__ outp,
                         int Bn, int Hin, int Win, int C)
{
    int OH = Hin >> 1, OW = Win >> 1, H2 = OH + 2, W2 = OW + 2;
    int total = Bn * H2 * W2 * C;
    int i = blockIdx.x * 256 + threadIdx.x;
    if (i >= total) return;
    int c = i % C; int t = i / C;
    int w = t % W2; t /= W2;
    int h = t % H2; int b = t / H2;
    u32 pv = 0;
    if (h >= 1 && h <= OH && w >= 1 && w <= OW) {
        int oh = h - 1, ow = w - 1;
        const float* p = in + (((size_t)b * Hin + 2 * oh) * Win + 2 * ow) * C + c;
        size_t rs = (size_t)Win * C;
        float v = fmaxf(fmaxf(p[0], p[C]), fmaxf(p[rs], p[rs + C]));
        pv = packsplit(fmaxf(v, 0.f));
    }
    outp[i] = pv;
}

// relu (no pool): [B][Hin][Win][C] fp32 -> halo'd packed [B][Hin+2][Win+2][C]
__global__ __launch_bounds__(256)
void pack_cl_kernel(const float* __restrict__ in, u32* __restrict__ outp,
                    int Bn, int Hin, int Win, int C)
{
    int H2 = Hin + 2, W2 = Win + 2;
    int total = Bn * H2 * W2 * C;
    int i = blockIdx.x * 256 + threadIdx.x;
    if (i >= total) return;
    int c = i % C; int t = i / C;
    int w = t % W2; t /= W2;
    int h = t % H2; int b = t / H2;
    u32 pv = 0;
    if (h >= 1 && h <= Hin && w >= 1 && w <= Win) {
        float v = in[(((size_t)b * Hin + (h - 1)) * Win + (w - 1)) * C + c];
        pv = packsplit(fmaxf(v, 0.f));
    }
    outp[i] = pv;
}

// L5 out [B][4][4][256] fp32 --relu+pool--> packed hT[b][f]
__global__ __launch_bounds__(256)
void pool_flatten_cl_kernel(const float* __restrict__ in, u32* __restrict__ outp)
{
    int i = blockIdx.x * 256 + threadIdx.x;
    if (i >= 512 * 1024) return;
    int b = i >> 10;
    int f = i & 1023;
    int c = f >> 2, sp = f & 3;
    int oh = sp >> 1, ow = sp & 1;
    const float* p = in + (((size_t)b * 4 + 2 * oh) * 4 + 2 * ow) * 256 + c;
    float v = fmaxf(fmaxf(p[0], p[256]), fmaxf(p[1024], p[1024 + 256]));
    outp[i] = packsplit(fmaxf(v, 0.f));
}

// FC act: fp32 [Mt][Nt] --relu--> packed transposed [Nt][Mt]
__global__ __launch_bounds__(256)
void tp_pack_kernel(const float* __restrict__ in, u32* __restrict__ outp,
                    int Mt, int Nt)
{
    __shared__ float t[32][33];
    int tx = threadIdx.x & 31, ty = threadIdx.x >> 5;
    int mB = blockIdx.x << 5, nB = blockIdx.y << 5;
#pragma unroll
    for (int i = 0; i < 4; ++i) {
        int mm = ty + i * 8;
        t[mm][tx] = in[(size_t)(mB + mm) * Nt + nB + tx];
    }
    __syncthreads();
#pragma unroll
    for (int i = 0; i < 4; ++i) {
        int nn = ty + i * 8;
        float v = fmaxf(t[tx][nn], 0.f);
        outp[(size_t)(nB + nn) * Mt + mB + tx] = packsplit(v);
    }
}

extern "C" void kernel_launch(void* const* d_in, const int* in_sizes, int n_in,
                              void* d_out, int out_size, void* d_ws, size_t ws_size,
                              hipStream_t stream)
{
    const float* x    = (const float*)d_in[0];
    const float* dw1  = (const float*)d_in[1];
    const float* rw1  = (const float*)d_in[2];
    const float* rb1  = (const float*)d_in[3];
    const float* dw2  = (const float*)d_in[4];
    const float* rw2  = (const float*)d_in[5];
    const float* rb2  = (const float*)d_in[6];
    const float* dw3  = (const float*)d_in[7];
    const float* rw3  = (const float*)d_in[8];
    const float* rb3  = (const float*)d_in[9];
    const float* cw4  = (const float*)d_in[10];
    const float* cr4w = (const float*)d_in[11];
    const float* cr4b = (const float*)d_in[12];
    const float* cw5  = (const float*)d_in[13];
    const float* cr5w = (const float*)d_in[14];
    const float* cr5b = (const float*)d_in[15];
    const float* fw1  = (const float*)d_in[16];
    const float* fb1  = (const float*)d_in[17];
    const float* fw2  = (const float*)d_in[18];
    const float* fb2  = (const float*)d_in[19];
    const float* fw3  = (const float*)d_in[20];
    const float* fb3  = (const float*)d_in[21];
    float* out = (float*)d_out;

    // ---- workspace (float units); layout as R10 ----
    float* ws    = (float*)d_ws;
    float* r1    = ws;
    float* r2    = r1 + 1536;
    float* r3    = r2 + 1536;
    float* r4    = r3 + 1536;
    float* r5    = r4 + 1536;
    float* sdesc = ws + 8192 + 65536;
    const size_t REGION = 18874368;           // 75.5 MB region
    float* region = sdesc + 196608;
    float* slab   = region;                   // fp32 out-slab (front)
    u32*   a3u    = (u32*)(region + 4194304); // [512][6][6][384] packed u32
    u16*   regEnd = (u16*)(region + REGION);
    u32*   P1     = (u32*)(region + REGION);  // 6,291,456 u32 (25.2 MB)

    u16 *w1h = regEnd - 2*(size_t)6144,     *w1l = regEnd - (size_t)6144;
    u16 *w2h = regEnd - 2*(size_t)331776,   *w2l = regEnd - (size_t)331776;
    u16 *w3h = regEnd - 2*(size_t)1990656,  *w3l = regEnd - (size_t)1990656;
    u16 *w4h = regEnd - 2*(size_t)2654208,  *w4l = regEnd - (size_t)2654208;
    u16 *w5h = regEnd - 2*(size_t)1769472,  *w5l = regEnd - (size_t)1769472;
    u16 *f1h = regEnd - 2*(size_t)4194304,  *f1l = regEnd - (size_t)4194304;
    u16 *f2h = regEnd - 2*(size_t)16777216, *f2l = regEnd - (size_t)16777216;
    u16 *f3h = regEnd - 2*(size_t)409600,   *f3l = regEnd - (size_t)409600;

    u32* xpk   = P1;                 // [B][3][32][32]
    u32* a1    = P1;                 // [512][10][10][64]
    u32* a2    = P1;                 // [512][6][6][192]
    u32* a4    = P1;                 // [512][6][6][256]
    u32* hTpk  = P1;                 // [512][1024]
    u32* f1pkT = P1 + 1048576;
    u32* f2pkT = P1 + 3145728;

    const int B = 512;

    // ---- input pack ----
    pack_kernel<<<6144, 256, 0, stream>>>(x, xpk, 1572864);

    // ---- Layer 1: DyRes conv 3->64, s2 p1 -> slab [B][16][16][64] ----
    wsplit_kernel<<<24, 256, 0, stream>>>(dw1, w1h, w1l, 6144, 27, 32);
    stats_kernel<<<B * 3, 64, 0, stream>>>(x, sdesc, 3, 1024, 1);
    routing_kernel<<<B, 64, 0, stream>>>(sdesc, rw1, rb1, r1, 3, 1);
    cgemm_l1_kernel<<<dim3(1024, 1, 1), 256, 0, stream>>>(
        w1h, w1l, xpk, r1, slab, 64, 131072);
    pool_pack_cl_kernel<<<12800, 256, 0, stream>>>(slab, a1, B, 16, 16, 64);

    // ---- Layer 2: DyRes conv 64->192 -> slab [B][8][8][192] ----
    wsplit_cl_kernel<<<1296, 256, 0, stream>>>(dw2, w2h, w2l, 331776, 64);
    stats_cl_kernel<<<B, 64, 0, stream>>>(a1, sdesc, 10, 10, 64, 1);
    routing_kernel<<<B, 64, 0, stream>>>(sdesc, rw2, rb2, r2, 64, 1);
    cgemm_cl_kernel<64, 10, 10, 6, 3><<<dim3(256, 2, 1), 256, 0, stream>>>(
        w2h, w2l, a1, r2, slab, 192, 32768, 576, 576);
    pool_pack_cl_kernel<<<13824, 256, 0, stream>>>(slab, a2, B, 8, 8, 192);

    // ---- Layer 3: DyRes conv 192->384 -> slab [B][4][4][384] ----
    wsplit_cl_kernel<<<7776, 256, 0, stream>>>(dw3, w3h, w3l, 1990656, 192);
    stats_cl_kernel<<<B, 192, 0, stream>>>(a2, sdesc, 6, 6, 192, 1);
    routing_kernel<<<B, 64, 0, stream>>>(sdesc, rw3, rb3, r3, 192, 1);
    hipMemsetAsync(slab, 0, (size_t)8192 * 384 * 4, stream);
    cgemm_cl_kernel<192, 6, 6, 4, 2><<<dim3(64, 3, 2), 256, 0, stream>>>(
        w3h, w3l, a2, r3, slab, 384, 8192, 1728, 864);
    pack_cl_kernel<<<27648, 256, 0, stream>>>(slab, a3u, B, 4, 4, 384);

    // ---- Layer 4: CondConv 384->256 -> slab [B][4][4][256] ----
    wsplit_cl_kernel<<<10368, 256, 0, stream>>>(cw4, w4h, w4l, 2654208, 384);
    stats_cl_kernel<<<B, 384, 0, stream>>>(a3u, sdesc, 6, 6, 384, 0);
    routing_kernel<<<B, 64, 0, stream>>>(sdesc, cr4w, cr4b, r4, 384, 0);
    hipMemsetAsync(slab, 0, (size_t)8192 * 256 * 4, stream);
    cgemm_cl_kernel<384, 6, 6, 4, 2><<<dim3(64, 2, 4), 256, 0, stream>>>(
        w4h, w4l, a3u, r4, slab, 256, 8192, 3456, 864);
    pack_cl_kernel<<<18432, 256, 0, stream>>>(slab, a4, B, 4, 4, 256);

    // ---- Layer 5: CondConv 256->256 -> slab [B][4][4][256] ----
    wsplit_cl_kernel<<<6912, 256, 0, stream>>>(cw5, w5h, w5l, 1769472, 256);
    stats_cl_kernel<<<B, 256, 0, stream>>>(a4, sdesc, 6, 6, 256, 0);
    routing_kernel<<<B, 64, 0, stream>>>(sdesc, cr5w, cr5b, r5, 256, 0);
    hipMemsetAsync(slab, 0, (size_t)8192 * 256 * 4, stream);
    cgemm_cl_kernel<256, 6, 6, 4, 2><<<dim3(64, 2, 4), 256, 0, stream>>>(
        w5h, w5l, a4, r5, slab, 256, 8192, 2304, 576);

    // ---- relu + pool + flatten -> packed hT [512][1024] ----
    pool_flatten_cl_kernel<<<2048, 256, 0, stream>>>(slab, hTpk);

    // ---- FC1: 1024 -> 4096 ----
    wsplit_kernel<<<16384, 256, 0, stream>>>(fw1, f1h, f1l, 4194304, 1024, 1024);
    hipMemsetAsync(slab, 0, (size_t)4096 * 512 * 4, stream);
    mgemm_kernel<1, 0><<<dim3(4, 32, 8), 256, 0, stream>>>(
        f1h, f1l, hTpk, fb1, slab, 4096, 512, 1024, 128);
    tp_pack_kernel<<<dim3(128, 16), 256, 0, stream>>>(slab, f1pkT, 4096, 512);

    // ---- FC2: 4096 -> 4096 ----
    wsplit_kernel<<<65536, 256, 0, stream>>>(fw2, f2h, f2l, 16777216, 4096, 4096);
    hipMemsetAsync(slab, 0, (size_t)4096 * 512 * 4, stream);
    mgemm_kernel<1, 0><<<dim3(4, 32, 8), 256, 0, stream>>>(
        f2h, f2l, f1pkT, fb2, slab, 4096, 512, 4096, 512);
    tp_pack_kernel<<<dim3(128, 16), 256, 0, stream>>>(slab, f2pkT, 4096, 512);

    // ---- FC3: 4096 -> 100 -> d_out [512, 100] ----
    wsplit_kernel<<<1600, 256, 0, stream>>>(fw3, f3h, f3l, 409600, 4096, 4096);
    hipMemsetAsync(out, 0, (size_t)512 * 100 * 4, stream);
    mgemm_kernel<1, 1><<<dim3(4, 1, 32), 256, 0, stream>>>(
        f3h, f3l, f2pkT, fb3, out, 100, 512, 4096, 128);
}